// Round 9
// baseline (623.952 us; speedup 1.0000x reference)
//
#include <hip/hip_runtime.h>
#include <hip/hip_cooperative_groups.h>
#include <cstdint>
#include <cstddef>

namespace cg = cooperative_groups;

using short8  = __attribute__((ext_vector_type(8))) short;
using floatx4 = __attribute__((ext_vector_type(4))) float;

#define DEV __device__ __forceinline__

DEV float u2f(unsigned short u){
  union { unsigned int i; float f; } c; c.i = ((unsigned int)u) << 16; return c.f;
}
DEV unsigned short f2u(float f){
  union { float f; unsigned int i; } c; c.f = f;
  unsigned int i = c.i;
  i += 0x7fffu + ((i >> 16) & 1u);   // RNE to bf16 (finite values only here)
  return (unsigned short)(i >> 16);
}
DEV float sigmoidf_(float x){ return 1.0f / (1.0f + __expf(-x)); }
DEV float siluf_(float x){ return x / (1.0f + __expf(-x)); }

#define ASYNC_LD16(g, l) __builtin_amdgcn_global_load_lds( \
    (const __attribute__((address_space(1))) unsigned int*)(g), \
    (__attribute__((address_space(3))) unsigned int*)(l), 16, 0, 0)

#define MFMA_BF16 __builtin_amdgcn_mfma_f32_16x16x32_bf16

// raw barrier: opaque to waitcnt-insertion, no implicit vmcnt(0) drain (R3-proven)
#define SBAR() asm volatile("s_barrier" ::: "memory")
#define LGKM0() asm volatile("s_waitcnt lgkmcnt(0)" ::: "memory")

constexpr float SCALING = 0.088388347648318447f; // 128^-0.5

// ---------------------------------------------------------------- params
struct KP {
  const float *query, *key, *Wq, *bq, *Wk, *bk, *Wv, *bv, *Wh, *bh, *gamma, *beta;
  float* out;
  unsigned short *qbf, *kbr, *Wqb, *Wkb, *Wvb, *Whb, *ub, *rbf, *qpj, *kpj, *vT, *hrb;
  int* wq;
};

// ---------------------------------------------------------------- stage 0: casts
// r in [0,20736): [0,8192) query rows; [8192,16384) key rows (batch de-interleave);
// [16384,18560) Wq; [18560,18688) Wk; [18688,19712) Wv; [19712,20736) Wh.
DEV void dev_cast(int r, int e, const KP& p)
{
  const float* src; unsigned short* dst;
  if (r < 8192) {
    src = p.query + (long long)r * 1024;
    dst = p.qbf   + (long long)r * 1024;
  } else if (r < 16384) {
    const int m = r - 8192;
    const int s = m >> 2, b = m & 3;
    src = p.key + (long long)m * 1024;
    dst = p.kbr + ((long long)b * 2048 + s) * 1024;
  } else if (r < 18560) { src = p.Wq + (long long)(r-16384) * 1024; dst = p.Wqb + (long long)(r-16384) * 1024; }
  else if (r < 18688)   { src = p.Wk + (long long)(r-18560) * 1024; dst = p.Wkb + (long long)(r-18560) * 1024; }
  else if (r < 19712)   { src = p.Wv + (long long)(r-18688) * 1024; dst = p.Wvb + (long long)(r-18688) * 1024; }
  else                  { src = p.Wh + (long long)(r-19712) * 1024; dst = p.Whb + (long long)(r-19712) * 1024; }
  const float4 v = *(const float4*)(src + e);
  ushort4 o; o.x=f2u(v.x); o.y=f2u(v.y); o.z=f2u(v.z); o.w=f2u(v.w);
  *(ushort4*)(dst + e) = o;
}

// ---------------------------------------------------------------- stage 1: mega body (R8-exact)
// lb <256: g0 (256x256 counted-vmcnt GEMM, Wq-main -> u,r)
// lb <512: g2 (256x128 2-phase, vT = silu(Wv @ kbr^T + bv))
// lb <576: proj (q-slice / k-proj, silu*g+b epilogue)
DEV void dev_mega(int lb, unsigned short* __restrict__ Ls, const KP& p, int tid)
{
  const int lane = tid & 63;
  const int wv   = tid >> 6;
  const int lr   = lane & 15;
  const int lq   = lane >> 4;
  const int r7   = lr & 7;
  const floatx4 zero = {0.f, 0.f, 0.f, 0.f};

  if (lb < 256) {
    const int bm = lb & 31, bn = lb >> 5;
    const int row0 = bm * 256;
    const int col0 = bn * 256;
    const int lda = 1024, ldb = 1024;
    const int wr = (wv >> 2) * 128;
    const int wc = (wv & 3) * 64;

    const int rr0 = tid >> 3;
    const int swz = ((tid & 7) ^ (rr0 & 7)) * 8;
    const unsigned short* gA0 = p.qbf + (long long)(row0 + rr0) * lda + swz;
    const unsigned short* gB0 = p.Wqb + (long long)(col0 + rr0) * ldb + swz;
    const long long sA64 = 64LL * lda, sB64 = 64LL * ldb;
    unsigned short* lA0 = Ls         + tid * 8;
    unsigned short* lB0 = Ls + 16384 + tid * 8;

    floatx4 acc[8][4];
    #pragma unroll
    for (int i = 0; i < 8; i++)
      #pragma unroll
      for (int j = 0; j < 4; j++) acc[i][j] = zero;

    const int NT = 16;

    #pragma unroll
    for (int i = 0; i < 4; i++) ASYNC_LD16(gA0 + i * sA64,      lA0 + i * 4096);
    #pragma unroll
    for (int i = 0; i < 4; i++) ASYNC_LD16(gB0 + i * sB64,      lB0 + i * 4096);
    #pragma unroll
    for (int i = 0; i < 4; i++) ASYNC_LD16(gA0 + i * sA64 + 64, lA0 + i * 4096 + 32768);
    #pragma unroll
    for (int i = 0; i < 4; i++) ASYNC_LD16(gB0 + i * sB64 + 64, lB0 + i * 4096 + 32768);
    asm volatile("s_waitcnt vmcnt(8)" ::: "memory");
    SBAR();

    for (int t = 0; t < NT; ++t) {
      const int cb = (t & 1) << 15;
      const unsigned short* Ab = Ls + cb;
      const unsigned short* Bb = Ls + cb + 16384;
      const bool st = (t + 2) < NT;
      const int kt2 = (t + 2) << 6;

      short8 afA[4][2], afB[4][2], bf01[2][2], bf23[2][2];

      #pragma unroll
      for (int mi = 0; mi < 4; mi++)
        #pragma unroll
        for (int kk = 0; kk < 2; kk++)
          afA[mi][kk] = *(const short8*)(Ab + (wr + mi*16 + lr) * 64 + (((kk<<2) + lq) ^ r7) * 8);
      #pragma unroll
      for (int ni = 0; ni < 2; ni++)
        #pragma unroll
        for (int kk = 0; kk < 2; kk++)
          bf01[ni][kk] = *(const short8*)(Bb + (wc + ni*16 + lr) * 64 + (((kk<<2) + lq) ^ r7) * 8);
      #pragma unroll
      for (int ni = 0; ni < 2; ni++)
        #pragma unroll
        for (int kk = 0; kk < 2; kk++)
          bf23[ni][kk] = *(const short8*)(Bb + (wc + (ni+2)*16 + lr) * 64 + (((kk<<2) + lq) ^ r7) * 8);
      __builtin_amdgcn_s_setprio(1);
      #pragma unroll
      for (int mi = 0; mi < 4; mi++)
        #pragma unroll
        for (int ni = 0; ni < 2; ni++)
          #pragma unroll
          for (int kk = 0; kk < 2; kk++)
            acc[mi][ni] = MFMA_BF16(afA[mi][kk], bf01[ni][kk], acc[mi][ni], 0, 0, 0);
      #pragma unroll
      for (int mi = 0; mi < 4; mi++)
        #pragma unroll
        for (int ni = 0; ni < 2; ni++)
          #pragma unroll
          for (int kk = 0; kk < 2; kk++)
            acc[mi][ni+2] = MFMA_BF16(afA[mi][kk], bf23[ni][kk], acc[mi][ni+2], 0, 0, 0);
      __builtin_amdgcn_s_setprio(0);
      LGKM0();
      SBAR();

      #pragma unroll
      for (int mi = 0; mi < 4; mi++)
        #pragma unroll
        for (int kk = 0; kk < 2; kk++)
          afB[mi][kk] = *(const short8*)(Ab + (wr + (mi+4)*16 + lr) * 64 + (((kk<<2) + lq) ^ r7) * 8);
      if (st) {
        #pragma unroll
        for (int i = 0; i < 4; i++) ASYNC_LD16(gB0 + i * sB64 + kt2, lB0 + i * 4096 + cb);
      }
      __builtin_amdgcn_s_setprio(1);
      #pragma unroll
      for (int mi = 0; mi < 4; mi++)
        #pragma unroll
        for (int ni = 0; ni < 2; ni++)
          #pragma unroll
          for (int kk = 0; kk < 2; kk++)
            acc[mi+4][ni] = MFMA_BF16(afB[mi][kk], bf01[ni][kk], acc[mi+4][ni], 0, 0, 0);
      __builtin_amdgcn_s_setprio(0);
      LGKM0();
      SBAR();

      if (st) {
        #pragma unroll
        for (int i = 0; i < 4; i++) ASYNC_LD16(gA0 + i * sA64 + kt2, lA0 + i * 4096 + cb);
      }
      __builtin_amdgcn_s_setprio(1);
      #pragma unroll
      for (int mi = 0; mi < 4; mi++)
        #pragma unroll
        for (int ni = 0; ni < 2; ni++)
          #pragma unroll
          for (int kk = 0; kk < 2; kk++)
            acc[mi+4][ni+2] = MFMA_BF16(afB[mi][kk], bf23[ni][kk], acc[mi+4][ni+2], 0, 0, 0);
      __builtin_amdgcn_s_setprio(0);
      if (st) { asm volatile("s_waitcnt vmcnt(8)" ::: "memory"); }
      else    { asm volatile("s_waitcnt vmcnt(0)" ::: "memory"); }
      SBAR();
    }

    #pragma unroll
    for (int mi = 0; mi < 8; mi++)
      #pragma unroll
      for (int ni = 0; ni < 4; ni++)
        #pragma unroll
        for (int r = 0; r < 4; r++) {
          const int gm = row0 + wr + mi * 16 + lq * 4 + r;
          const int gn = col0 + wc + ni * 16 + lr;
          float v = acc[mi][ni][r] + p.bq[gn];
          if (gn < 1024) {
            p.ub[(long long)gm * 1024 + gn] = f2u(sigmoidf_(v));
          } else {
            p.rbf[(long long)gm * 1024 + (gn - 1024)] = f2u(siluf_(v));
          }
        }
  } else {
    const unsigned short* Ag; const unsigned short* Bg;
    int row0, col0, zproj = -1;
    if (lb < 512) {
      const int idx = lb - 256;
      row0 = (idx & 3) * 256;
      col0 = (idx >> 2) * 128;
      Ag = p.Wvb; Bg = p.kbr;
    } else {
      const int idx = lb - 512;
      zproj = idx >> 5;
      row0 = (idx & 31) * 256;
      col0 = 0;
      Ag = zproj ? p.kbr : p.qbf;
      Bg = zproj ? p.Wkb : (p.Wqb + 2048LL * 1024);
    }
    const int lda = 1024, ldb = 1024;
    const int wr = (wv & 3) * 64;
    const int wc = (wv >> 2) * 64;

    const int rr0 = tid >> 3;
    const int swz = ((tid & 7) ^ (rr0 & 7)) * 8;
    const unsigned short* gA0 = Ag + (long long)(row0 + rr0) * lda + swz;
    const unsigned short* gB0 = Bg + (long long)(col0 + rr0) * ldb + swz;
    const long long sA64 = 64LL * lda, sB64 = 64LL * ldb;
    unsigned short* lA0 = Ls         + tid * 8;
    unsigned short* lB0 = Ls + 16384 + tid * 8;

    floatx4 acc[4][4];
    #pragma unroll
    for (int i = 0; i < 4; i++)
      #pragma unroll
      for (int j = 0; j < 4; j++) acc[i][j] = zero;

    const int NT = 16;

    #pragma unroll
    for (int i = 0; i < 4; i++) ASYNC_LD16(gA0 + i * sA64,      lA0 + i * 4096);
    #pragma unroll
    for (int i = 0; i < 2; i++) ASYNC_LD16(gB0 + i * sB64,      lB0 + i * 4096);
    #pragma unroll
    for (int i = 0; i < 4; i++) ASYNC_LD16(gA0 + i * sA64 + 64, lA0 + i * 4096 + 24576);
    #pragma unroll
    for (int i = 0; i < 2; i++) ASYNC_LD16(gB0 + i * sB64 + 64, lB0 + i * 4096 + 24576);
    asm volatile("s_waitcnt vmcnt(6)" ::: "memory");
    SBAR();

    for (int t = 0; t < NT; ++t) {
      const int cb = (t & 1) * 24576;
      const unsigned short* Ab = Ls + cb;
      const unsigned short* Bb = Ls + cb + 16384;
      const bool st = (t + 2) < NT;
      const int kt2 = (t + 2) << 6;

      short8 afA[4][2], bfv[4][2];

      #pragma unroll
      for (int mi = 0; mi < 4; mi++)
        #pragma unroll
        for (int kk = 0; kk < 2; kk++)
          afA[mi][kk] = *(const short8*)(Ab + (wr + mi*16 + lr) * 64 + (((kk<<2) + lq) ^ r7) * 8);
      #pragma unroll
      for (int ni = 0; ni < 4; ni++)
        #pragma unroll
        for (int kk = 0; kk < 2; kk++)
          bfv[ni][kk] = *(const short8*)(Bb + (wc + ni*16 + lr) * 64 + (((kk<<2) + lq) ^ r7) * 8);
      LGKM0();
      __builtin_amdgcn_sched_barrier(0);
      __builtin_amdgcn_s_setprio(1);
      #pragma unroll
      for (int mi = 0; mi < 4; mi++)
        #pragma unroll
        for (int ni = 0; ni < 2; ni++)
          #pragma unroll
          for (int kk = 0; kk < 2; kk++)
            acc[mi][ni] = MFMA_BF16(afA[mi][kk], bfv[ni][kk], acc[mi][ni], 0, 0, 0);
      __builtin_amdgcn_s_setprio(0);
      SBAR();

      if (st) {
        #pragma unroll
        for (int i = 0; i < 4; i++) ASYNC_LD16(gA0 + i * sA64 + kt2, lA0 + i * 4096 + cb);
        #pragma unroll
        for (int i = 0; i < 2; i++) ASYNC_LD16(gB0 + i * sB64 + kt2, lB0 + i * 4096 + cb);
      }
      __builtin_amdgcn_s_setprio(1);
      #pragma unroll
      for (int mi = 0; mi < 4; mi++)
        #pragma unroll
        for (int ni = 0; ni < 2; ni++)
          #pragma unroll
          for (int kk = 0; kk < 2; kk++)
            acc[mi][ni+2] = MFMA_BF16(afA[mi][kk], bfv[ni+2][kk], acc[mi][ni+2], 0, 0, 0);
      __builtin_amdgcn_s_setprio(0);
      if (st) { asm volatile("s_waitcnt vmcnt(6)" ::: "memory"); }
      else    { asm volatile("s_waitcnt vmcnt(0)" ::: "memory"); }
      SBAR();
    }

    if (zproj < 0) {
      #pragma unroll
      for (int mi = 0; mi < 4; mi++)
        #pragma unroll
        for (int ni = 0; ni < 4; ni++)
          #pragma unroll
          for (int r = 0; r < 4; r++) {
            const int gm = row0 + wr + mi * 16 + lq * 4 + r;
            const int gn = col0 + wc + ni * 16 + lr;
            const float v = acc[mi][ni][r] + p.bv[gm];
            const int b = gn >> 11, s = gn & 2047;
            p.vT[((long long)b * 1024 + gm) * 2048 + s] = f2u(siluf_(v));
          }
    } else {
      const float* bias = zproj ? p.bk : (p.bq + 2048);
      const float* gam  = zproj ? (p.gamma + 128) : p.gamma;
      const float* bet  = zproj ? (p.beta + 128)  : p.beta;
      unsigned short* ob = zproj ? p.kpj : p.qpj;
      #pragma unroll
      for (int mi = 0; mi < 4; mi++)
        #pragma unroll
        for (int ni = 0; ni < 4; ni++)
          #pragma unroll
          for (int r = 0; r < 4; r++) {
            const int gm = row0 + wr + mi * 16 + lq * 4 + r;
            const int gn = wc + ni * 16 + lr;
            const float v = acc[mi][ni][r] + bias[gn];
            ob[(long long)gm * 128 + gn] = f2u(siluf_(v) * gam[gn] + bet[gn]);
          }
    }
  }
}

// ---------------------------------------------------------------- stage 2: attn body (R7-exact, 75us)
// pool layout: Vs @0 (65536 B), Ks @65536 (32768 B), Ps @98304 (8192 B), rsl @106496
DEV void dev_attn(int bid, unsigned char* __restrict__ pool, const KP& p, int tid)
{
  unsigned short* Vs = (unsigned short*)(pool);
  unsigned short* Ks = (unsigned short*)(pool + 65536);
  unsigned short* Ps = (unsigned short*)(pool + 98304);
  float*         rsl = (float*)(pool + 106496);

  const int eh = bid & 1, ty = (bid >> 1) & 31, bz = bid >> 6;
  const int t0 = ty * 64;

  const int lane = tid & 63;
  const int wv   = tid >> 6;
  const int lr   = lane & 15;
  const int lq   = lane >> 4;
  const int mi_s = wv & 3;
  const int niA  = (wv >> 2) * 2;

  const unsigned short* kb_g = p.kpj + (long long)bz * 2048 * 128;
  const unsigned short* vb_g = p.vT  + (long long)bz * 1024 * 2048;

  short8 afq[4];
  {
    const unsigned short* qrow = p.qpj + (long long)bz * 128
                               + (long long)(t0 + mi_s * 16 + lr) * 512;
    #pragma unroll
    for (int kd = 0; kd < 4; kd++)
      afq[kd] = *(const short8*)(qrow + (kd * 4 + lq) * 8);
  }

  const int rrV = tid >> 3;
  const int gcV = ((tid & 7) ^ (rrV & 7)) * 8;
  const unsigned short* gV0 = vb_g + (long long)(eh * 512 + rrV) * 2048 + gcV;
  unsigned short* lV0 = Vs + tid * 8;
  const int rrK = tid >> 4;
  const int gcK = ((tid & 15) ^ (rrK & 15)) * 8;
  const unsigned short* gK0 = kb_g + (long long)rrK * 128 + gcK;
  unsigned short* lK0 = Ks + tid * 8;

  floatx4 acc[4][4];
  floatx4 accSum[4];
  const floatx4 zero = {0.f, 0.f, 0.f, 0.f};
  #pragma unroll
  for (int i = 0; i < 4; i++) {
    accSum[i] = zero;
    #pragma unroll
    for (int j = 0; j < 4; j++) acc[i][j] = zero;
  }
  const short ob = (short)0x3F80;
  const short8 ones = {ob, ob, ob, ob, ob, ob, ob, ob};

  #pragma unroll
  for (int i = 0; i < 2; i++) ASYNC_LD16(gK0 + i * 4096, lK0 + i * 4096);

  for (int t = 0; t < 32; ++t) {
    const unsigned short* Kb = Ks + (t & 1) * 8192;
    const bool st = (t + 1) < 32;

    #pragma unroll
    for (int i = 0; i < 8; i++)
      ASYNC_LD16(gV0 + (long long)i * 131072 + t * 64, lV0 + i * 4096);
    if (st) {
      unsigned short* lKn = Ks + ((t + 1) & 1) * 8192 + tid * 8;
      #pragma unroll
      for (int i = 0; i < 2; i++)
        ASYNC_LD16(gK0 + (long long)(t + 1) * 8192 + i * 4096, lKn + i * 4096);
    }
    if (st) { asm volatile("s_waitcnt vmcnt(10)" ::: "memory"); }
    else    { asm volatile("s_waitcnt vmcnt(8)"  ::: "memory"); }
    SBAR();

    floatx4 accS[2] = {zero, zero};
    short8 bfk[2][4];
    #pragma unroll
    for (int f = 0; f < 2; f++)
      #pragma unroll
      for (int kd = 0; kd < 4; kd++)
        bfk[f][kd] = *(const short8*)(Kb + ((niA + f) * 16 + lr) * 128
                                         + (((kd * 4 + lq) ^ lr) & 15) * 8);
    #pragma unroll
    for (int f = 0; f < 2; f++)
      #pragma unroll
      for (int kd = 0; kd < 4; kd++)
        accS[f] = MFMA_BF16(afq[kd], bfk[f][kd], accS[f], 0, 0, 0);
    #pragma unroll
    for (int f = 0; f < 2; f++) {
      const int nif = niA + f;
      #pragma unroll
      for (int r = 0; r < 4; r++) {
        const float e = __expf(accS[f][r] * SCALING);
        const int trow = mi_s * 16 + lq * 4 + r;
        const int scol = nif * 16 + lr;
        const int slot = (scol >> 3) ^ (trow & 7);
        Ps[trow * 64 + slot * 8 + (lr & 7)] = f2u(e);
      }
    }
    LGKM0();
    if (st) { asm volatile("s_waitcnt vmcnt(2)" ::: "memory"); }
    else    { asm volatile("s_waitcnt vmcnt(0)" ::: "memory"); }
    SBAR();

    short8 afP[4][2], bfv[4][2];
    #pragma unroll
    for (int mi = 0; mi < 4; mi++)
      #pragma unroll
      for (int k8 = 0; k8 < 2; k8++)
        afP[mi][k8] = *(const short8*)(Ps + (mi * 16 + lr) * 64
                                          + ((k8 * 4 + lq) ^ (lr & 7)) * 8);
    #pragma unroll
    for (int ni = 0; ni < 4; ni++)
      #pragma unroll
      for (int k8 = 0; k8 < 2; k8++)
        bfv[ni][k8] = *(const short8*)(Vs + (wv * 64 + ni * 16 + lr) * 64
                                          + ((k8 * 4 + lq) ^ (lr & 7)) * 8);
    __builtin_amdgcn_s_setprio(1);
    #pragma unroll
    for (int mi = 0; mi < 4; mi++)
      #pragma unroll
      for (int ni = 0; ni < 4; ni++)
        #pragma unroll
        for (int k8 = 0; k8 < 2; k8++)
          acc[mi][ni] = MFMA_BF16(afP[mi][k8], bfv[ni][k8], acc[mi][ni], 0, 0, 0);
    __builtin_amdgcn_s_setprio(0);
    if (wv == 0) {
      #pragma unroll
      for (int mi = 0; mi < 4; mi++)
        #pragma unroll
        for (int k8 = 0; k8 < 2; k8++)
          accSum[mi] = MFMA_BF16(afP[mi][k8], ones, accSum[mi], 0, 0, 0);
    }
    LGKM0();
    SBAR();
  }

  if (wv == 0 && lr == 0) {
    #pragma unroll
    for (int mi = 0; mi < 4; mi++)
      #pragma unroll
      for (int r = 0; r < 4; r++)
        rsl[mi * 16 + lq * 4 + r] = accSum[mi][r];
  }
  LGKM0();
  SBAR();
  #pragma unroll
  for (int mi = 0; mi < 4; mi++) {
    float iv[4];
    #pragma unroll
    for (int r = 0; r < 4; r++) iv[r] = 1.0f / rsl[mi * 16 + lq * 4 + r];
    #pragma unroll
    for (int ni = 0; ni < 4; ni++) {
      #pragma unroll
      for (int r = 0; r < 4; r++) {
        const int gt = t0 + mi * 16 + lq * 4 + r;
        const int ge = eh * 512 + wv * 64 + ni * 16 + lr;
        const long long idx = ((long long)gt * 4 + bz) * 1024 + ge;
        p.hrb[idx] = f2u(acc[mi][ni][r] * iv[r] * u2f(p.rbf[idx]));
      }
    }
  }
}

// ---------------------------------------------------------------- stage 3: g5 body (R4-exact)
DEV void dev_g5(int bid, unsigned short* __restrict__ Ls, const KP& p, int tid)
{
  const int bm = bid & 31, bn = bid >> 5;
  const int row0 = bm * 256;
  const int col0 = bn * 128;
  const int lda = 1024, ldb = 1024;

  const int lane = tid & 63;
  const int wv   = tid >> 6;
  const int wr   = (wv & 3) * 64;
  const int wc   = (wv >> 2) * 64;
  const int lr   = lane & 15;
  const int lq   = lane >> 4;
  const int r7   = lr & 7;

  const int rr0 = tid >> 3;
  const int swz = ((tid & 7) ^ (rr0 & 7)) * 8;
  const unsigned short* gA0 = p.hrb + (long long)(row0 + rr0) * lda + swz;
  const unsigned short* gB0 = p.Whb + (long long)(col0 + rr0) * ldb + swz;
  const long long sA64 = 64LL * lda, sB64 = 64LL * ldb;
  unsigned short* lA0 = Ls         + tid * 8;
  unsigned short* lB0 = Ls + 16384 + tid * 8;

  floatx4 acc[4][4];
  const floatx4 zero = {0.f, 0.f, 0.f, 0.f};
  #pragma unroll
  for (int i = 0; i < 4; i++)
    #pragma unroll
    for (int j = 0; j < 4; j++) acc[i][j] = zero;

  const int NT = 16;

  #pragma unroll
  for (int i = 0; i < 4; i++) ASYNC_LD16(gA0 + i * sA64,      lA0 + i * 4096);
  #pragma unroll
  for (int i = 0; i < 2; i++) ASYNC_LD16(gB0 + i * sB64,      lB0 + i * 4096);
  #pragma unroll
  for (int i = 0; i < 4; i++) ASYNC_LD16(gA0 + i * sA64 + 64, lA0 + i * 4096 + 24576);
  #pragma unroll
  for (int i = 0; i < 2; i++) ASYNC_LD16(gB0 + i * sB64 + 64, lB0 + i * 4096 + 24576);
  asm volatile("s_waitcnt vmcnt(6)" ::: "memory");
  SBAR();

  for (int t = 0; t < NT; ++t) {
    const int cb = (t & 1) * 24576;
    const unsigned short* Ab = Ls + cb;
    const unsigned short* Bb = Ls + cb + 16384;
    const bool st = (t + 2) < NT;
    const int kt2 = (t + 2) << 6;

    short8 afA[4][2], bfv[4][2];

    #pragma unroll
    for (int mi = 0; mi < 4; mi++)
      #pragma unroll
      for (int kk = 0; kk < 2; kk++)
        afA[mi][kk] = *(const short8*)(Ab + (wr + mi*16 + lr) * 64 + (((kk<<2) + lq) ^ r7) * 8);
    #pragma unroll
    for (int ni = 0; ni < 4; ni++)
      #pragma unroll
      for (int kk = 0; kk < 2; kk++)
        bfv[ni][kk] = *(const short8*)(Bb + (wc + ni*16 + lr) * 64 + (((kk<<2) + lq) ^ r7) * 8);
    LGKM0();
    __builtin_amdgcn_sched_barrier(0);
    __builtin_amdgcn_s_setprio(1);
    #pragma unroll
    for (int mi = 0; mi < 4; mi++)
      #pragma unroll
      for (int ni = 0; ni < 2; ni++)
        #pragma unroll
        for (int kk = 0; kk < 2; kk++)
          acc[mi][ni] = MFMA_BF16(afA[mi][kk], bfv[ni][kk], acc[mi][ni], 0, 0, 0);
    __builtin_amdgcn_s_setprio(0);
    SBAR();

    if (st) {
      #pragma unroll
      for (int i = 0; i < 4; i++) ASYNC_LD16(gA0 + i * sA64 + kt2, lA0 + i * 4096 + cb);
      #pragma unroll
      for (int i = 0; i < 2; i++) ASYNC_LD16(gB0 + i * sB64 + kt2, lB0 + i * 4096 + cb);
    }
    __builtin_amdgcn_s_setprio(1);
    #pragma unroll
    for (int mi = 0; mi < 4; mi++)
      #pragma unroll
      for (int ni = 0; ni < 2; ni++)
        #pragma unroll
        for (int kk = 0; kk < 2; kk++)
          acc[mi][ni+2] = MFMA_BF16(afA[mi][kk], bfv[ni+2][kk], acc[mi][ni+2], 0, 0, 0);
    __builtin_amdgcn_s_setprio(0);
    if (st) { asm volatile("s_waitcnt vmcnt(6)" ::: "memory"); }
    else    { asm volatile("s_waitcnt vmcnt(0)" ::: "memory"); }
    SBAR();
  }

  #pragma unroll
  for (int mi = 0; mi < 4; mi++)
    #pragma unroll
    for (int ni = 0; ni < 4; ni++)
      #pragma unroll
      for (int r = 0; r < 4; r++) {
        const int gm = row0 + wr + mi * 16 + lq * 4 + r;
        const int gn = col0 + wc + ni * 16 + lr;
        const long long idx = (long long)gm * 1024 + gn;
        const float tv = tanhf(acc[mi][ni][r] + p.bh[gn]);
        const float qv = p.query[idx];
        p.out[idx] = qv + u2f(p.ub[idx]) * (tv - qv);
      }
}

// ---------------------------------------------------------------- cooperative uber-kernel
// 256 blocks x 512 thr, 1 block/CU (128 KB LDS) -> co-residency guaranteed.
// stage0 casts (grid-stride) | sync | stage1 mega via atomic work-queue |
// sync | stage2 attn | sync | stage3 g5. Gaps between dependent dispatches
// (~10-25 us each, R7/R8 audit) collapse into 3 grid.sync()s.
__global__ __launch_bounds__(512, 2) void uber(KP p)
{
  __shared__ __align__(16) unsigned char pool[131072];
  __shared__ int lb_sh;
  const int tid = threadIdx.x;
  const int bid = blockIdx.x;
  cg::grid_group grid = cg::this_grid();

  // ---- stage 0: casts (row-pairs: 512 thr = 2 rows of 1024)
  for (int pp = bid; pp < 10368; pp += 256) {
    dev_cast(pp * 2 + (tid >> 8), (tid & 255) * 4, p);
  }
  if (bid == 0 && tid == 0) *p.wq = 0;   // reset work-queue each replay
  __threadfence();
  grid.sync();

  // ---- stage 1: mega (576 logical blocks, dynamic heavy-first queue)
  unsigned short* Ls = (unsigned short*)pool;
  for (;;) {
    if (tid == 0) lb_sh = atomicAdd(p.wq, 1);
    __syncthreads();
    const int lb = lb_sh;
    if (lb >= 576) break;
    dev_mega(lb, Ls, p, tid);
    __syncthreads();   // LDS reads of this body drained (its final SBAR) + lb_sh reuse
  }
  __threadfence();
  grid.sync();

  // ---- stage 2: fused attention (256 blocks exact)
  dev_attn(bid, pool, p, tid);
  __threadfence();
  grid.sync();

  // ---- stage 3: g5 (256 blocks exact)
  dev_g5(bid, Ls, p, tid);
}

// ---------------------------------------------------------------- fallback kernels (R8 path)
__global__ __launch_bounds__(256) void k_cast(KP p)
{
  dev_cast(blockIdx.x, threadIdx.x * 4, p);
}
__global__ __launch_bounds__(512, 2) void k_mega(KP p)
{
  __shared__ __align__(16) unsigned short Ls[65536];
  dev_mega(blockIdx.x, Ls, p, threadIdx.x);
}
__global__ __launch_bounds__(512, 2) void k_attn(KP p)
{
  __shared__ __align__(16) unsigned char pool[106752];
  dev_attn(blockIdx.x, pool, p, threadIdx.x);
}
__global__ __launch_bounds__(512, 2) void k_g5(KP p)
{
  __shared__ __align__(16) unsigned short Ls[49152];
  dev_g5(blockIdx.x, Ls, p, threadIdx.x);
}

// ---------------------------------------------------------------- launch
extern "C" void kernel_launch(void* const* d_in, const int* in_sizes, int n_in,
                              void* d_out, int out_size, void* d_ws, size_t ws_size,
                              hipStream_t stream)
{
  (void)in_sizes; (void)n_in; (void)out_size; (void)ws_size;

  char* wp = (char*)d_ws;
  auto take = [&](size_t bytes) -> char* {
    char* r = wp; wp += (bytes + 255) & ~(size_t)255; return r;
  };
  KP p;
  p.query = (const float*)d_in[0];
  p.key   = (const float*)d_in[1];
  p.Wq    = (const float*)d_in[2];
  p.bq    = (const float*)d_in[3];
  p.Wk    = (const float*)d_in[4];
  p.bk    = (const float*)d_in[5];
  p.Wv    = (const float*)d_in[6];
  p.bv    = (const float*)d_in[7];
  p.Wh    = (const float*)d_in[8];
  p.bh    = (const float*)d_in[9];
  p.gamma = (const float*)d_in[10];
  p.beta  = (const float*)d_in[11];
  p.out   = (float*)d_out;
  p.qbf = (unsigned short*)take(8192ULL * 1024 * 2);
  p.kbr = (unsigned short*)take(8192ULL * 1024 * 2);
  p.Wqb = (unsigned short*)take(2176ULL * 1024 * 2);
  p.Wkb = (unsigned short*)take(128ULL  * 1024 * 2);
  p.Wvb = (unsigned short*)take(1024ULL * 1024 * 2);
  p.Whb = (unsigned short*)take(1024ULL * 1024 * 2);
  p.ub  = (unsigned short*)take(8192ULL * 1024 * 2);
  p.rbf = (unsigned short*)take(8192ULL * 1024 * 2);
  p.qpj = (unsigned short*)take(8192ULL * 128 * 2);
  p.kpj = (unsigned short*)take(8192ULL * 128 * 2);
  p.vT  = (unsigned short*)take(4ULL * 1024 * 2048 * 2);
  p.hrb = (unsigned short*)take(8192ULL * 1024 * 2);
  p.wq  = (int*)take(256);

  void* args[] = { (void*)&p };
  hipError_t err = hipLaunchCooperativeKernel((const void*)uber,
                                              dim3(256), dim3(512),
                                              args, 0, stream);
  if (err != hipSuccess) {
    // bounded fallback: exact R8 4-dispatch pipeline from the same bodies
    k_cast<<<20736, 256, 0, stream>>>(p);
    k_mega<<<576, 512, 0, stream>>>(p);
    k_attn<<<256, 512, 0, stream>>>(p);
    k_g5<<<256, 512, 0, stream>>>(p);
  }
}

// Round 10
// 331.825 us; speedup vs baseline: 1.8804x; 1.8804x over previous
//
#include <hip/hip_runtime.h>
#include <cstdint>
#include <cstddef>

using short8  = __attribute__((ext_vector_type(8))) short;
using floatx4 = __attribute__((ext_vector_type(4))) float;

#define DEV __device__ __forceinline__

DEV float u2f(unsigned short u){
  union { unsigned int i; float f; } c; c.i = ((unsigned int)u) << 16; return c.f;
}
DEV unsigned short f2u(float f){
  union { float f; unsigned int i; } c; c.f = f;
  unsigned int i = c.i;
  i += 0x7fffu + ((i >> 16) & 1u);   // RNE to bf16 (finite values only here)
  return (unsigned short)(i >> 16);
}
DEV float sigmoidf_(float x){ return 1.0f / (1.0f + __expf(-x)); }
DEV float siluf_(float x){ return x / (1.0f + __expf(-x)); }

// async global->LDS, 16 B per lane; LDS dest must be wave-uniform base + lane*16
#define ASYNC_LD16(g, l) __builtin_amdgcn_global_load_lds( \
    (const __attribute__((address_space(1))) unsigned int*)(g), \
    (__attribute__((address_space(3))) unsigned int*)(l), 16, 0, 0)

#define MFMA_BF16 __builtin_amdgcn_mfma_f32_16x16x32_bf16

// raw barrier, opaque to the compiler's waitcnt-insertion pass: no implicit
// vmcnt(0) drain can be attached (R3-proven: 122us -> 53.8us on gemm256).
#define SBAR() asm volatile("s_barrier" ::: "memory")
#define LGKM0() asm volatile("s_waitcnt lgkmcnt(0)" ::: "memory")

// problem-fixed sizes: T=2048 S=2048 B=4 E=1024 Z=128
constexpr float SCALING = 0.088388347648318447f; // 128^-0.5

// ---------------------------------------------------------------- fused casts
// [0,8192): query rows -> qbf; [8192,16384): key -> kbr (batch de-interleave)
// [16384,18560): Wq; [18560,18688): Wk; [18688,19712): Wv; [19712,20736): Wh
__global__ __launch_bounds__(256) void cast_all(
    const float* __restrict__ q, const float* __restrict__ k,
    const float* __restrict__ Wq, const float* __restrict__ Wk,
    const float* __restrict__ Wv, const float* __restrict__ Wh,
    unsigned short* __restrict__ qo, unsigned short* __restrict__ ko,
    unsigned short* __restrict__ oq, unsigned short* __restrict__ ok,
    unsigned short* __restrict__ ov, unsigned short* __restrict__ oh)
{
  const int bid = blockIdx.x;
  const int e = threadIdx.x * 4;
  const float* src; unsigned short* dst;
  if (bid < 8192) {
    src = q + (long long)bid * 1024;
    dst = qo + (long long)bid * 1024;
  } else if (bid < 16384) {
    const int m = bid - 8192;
    const int s = m >> 2, b = m & 3;
    src = k + (long long)m * 1024;
    dst = ko + ((long long)b * 2048 + s) * 1024;
  } else if (bid < 18560) { src = Wq + (long long)(bid-16384) * 1024; dst = oq + (long long)(bid-16384) * 1024; }
  else if (bid < 18688)   { src = Wk + (long long)(bid-18560) * 1024; dst = ok + (long long)(bid-18560) * 1024; }
  else if (bid < 19712)   { src = Wv + (long long)(bid-18688) * 1024; dst = ov + (long long)(bid-18688) * 1024; }
  else                    { src = Wh + (long long)(bid-19712) * 1024; dst = oh + (long long)(bid-19712) * 1024; }
  const float4 v = *(const float4*)(src + e);
  ushort4 o; o.x=f2u(v.x); o.y=f2u(v.y); o.z=f2u(v.z); o.w=f2u(v.w);
  *(ushort4*)(dst + e) = o;
}

// ---------------------------------------------------------------- MEGA dispatch
// 576 blocks x 512 thr, one 128K LDS pool (all paths were 1 block/CU anyway).
// bid <256 : g0  = gemm256 body (R5-proven, 51.2us): Wq-main -> u, r
// bid <512 : g2  = gemm_n128<2> body (R4-proven): vT = silu(Wv @ kbr^T + bv)
// bid <576 : proj = same 2-phase 256x128 body, EPI1 epilogue:
//            z=0 q-slice (Wq rows 2048..2175) -> qpj ; z=1 k-proj -> kpj
// Heavy blocks first: light proj blocks tail-fill CUs as g0 blocks retire.
__global__ __launch_bounds__(512, 2)
void mega(const unsigned short* __restrict__ qbf,
          const unsigned short* __restrict__ Wqb,
          const unsigned short* __restrict__ kbr,
          const unsigned short* __restrict__ Wvb,
          const unsigned short* __restrict__ Wkb,
          const float* __restrict__ bq, const float* __restrict__ bk,
          const float* __restrict__ bv,
          const float* __restrict__ gamma, const float* __restrict__ beta,
          float* __restrict__ ub_f,          // u gate (bf16 via reinterpret)
          unsigned short* __restrict__ rbf,  // r
          unsigned short* __restrict__ vT,   // [B][E][S]
          unsigned short* __restrict__ qpj,  // (T,B,Z)
          unsigned short* __restrict__ kpj)  // [B][S][Z]
{
  __shared__ __align__(16) unsigned short Ls[65536]; // 128 KiB

  const int bid = blockIdx.x;
  const int tid = threadIdx.x;
  const int lane = tid & 63;
  const int wv   = tid >> 6;
  const int lr   = lane & 15;
  const int lq   = lane >> 4;
  const int r7   = lr & 7;

  const floatx4 zero = {0.f, 0.f, 0.f, 0.f};

  if (bid < 256) {
    // ================= g0: 256x256 counted-vmcnt GEMM (R5-exact body) =================
    const int bm = bid & 31, bn = bid >> 5;
    const int row0 = bm * 256;
    const int col0 = bn * 256;
    const int lda = 1024, ldb = 1024;
    const int wr = (wv >> 2) * 128;
    const int wc = (wv & 3) * 64;

    const int rr0 = tid >> 3;
    const int swz = ((tid & 7) ^ (rr0 & 7)) * 8;
    const unsigned short* gA0 = qbf + (long long)(row0 + rr0) * lda + swz;
    const unsigned short* gB0 = Wqb + (long long)(col0 + rr0) * ldb + swz;
    const long long sA64 = 64LL * lda, sB64 = 64LL * ldb;
    unsigned short* lA0 = &Ls[0]     + tid * 8;
    unsigned short* lB0 = &Ls[16384] + tid * 8;

    floatx4 acc[8][4];
    #pragma unroll
    for (int i = 0; i < 8; i++)
      #pragma unroll
      for (int j = 0; j < 4; j++) acc[i][j] = zero;

    const int NT = 16; // K=1024

    #pragma unroll
    for (int i = 0; i < 4; i++) ASYNC_LD16(gA0 + i * sA64,      lA0 + i * 4096);
    #pragma unroll
    for (int i = 0; i < 4; i++) ASYNC_LD16(gB0 + i * sB64,      lB0 + i * 4096);
    #pragma unroll
    for (int i = 0; i < 4; i++) ASYNC_LD16(gA0 + i * sA64 + 64, lA0 + i * 4096 + 32768);
    #pragma unroll
    for (int i = 0; i < 4; i++) ASYNC_LD16(gB0 + i * sB64 + 64, lB0 + i * 4096 + 32768);
    asm volatile("s_waitcnt vmcnt(8)" ::: "memory");
    SBAR();

    for (int t = 0; t < NT; ++t) {
      const int cb = (t & 1) << 15;
      const unsigned short* Ab = &Ls[cb];
      const unsigned short* Bb = &Ls[cb + 16384];
      const bool st = (t + 2) < NT;
      const int kt2 = (t + 2) << 6;

      short8 afA[4][2], afB[4][2], bf01[2][2], bf23[2][2];

      // ---- ph1+ph2 (fused): 16 ds_reads; 32 MFMA Q(0-3, 0-3)
      #pragma unroll
      for (int mi = 0; mi < 4; mi++)
        #pragma unroll
        for (int kk = 0; kk < 2; kk++)
          afA[mi][kk] = *(const short8*)(Ab + (wr + mi*16 + lr) * 64 + (((kk<<2) + lq) ^ r7) * 8);
      #pragma unroll
      for (int ni = 0; ni < 2; ni++)
        #pragma unroll
        for (int kk = 0; kk < 2; kk++)
          bf01[ni][kk] = *(const short8*)(Bb + (wc + ni*16 + lr) * 64 + (((kk<<2) + lq) ^ r7) * 8);
      #pragma unroll
      for (int ni = 0; ni < 2; ni++)
        #pragma unroll
        for (int kk = 0; kk < 2; kk++)
          bf23[ni][kk] = *(const short8*)(Bb + (wc + (ni+2)*16 + lr) * 64 + (((kk<<2) + lq) ^ r7) * 8);
      __builtin_amdgcn_s_setprio(1);
      #pragma unroll
      for (int mi = 0; mi < 4; mi++)
        #pragma unroll
        for (int ni = 0; ni < 2; ni++)
          #pragma unroll
          for (int kk = 0; kk < 2; kk++)
            acc[mi][ni] = MFMA_BF16(afA[mi][kk], bf01[ni][kk], acc[mi][ni], 0, 0, 0);
      #pragma unroll
      for (int mi = 0; mi < 4; mi++)
        #pragma unroll
        for (int ni = 0; ni < 2; ni++)
          #pragma unroll
          for (int kk = 0; kk < 2; kk++)
            acc[mi][ni+2] = MFMA_BF16(afA[mi][kk], bf23[ni][kk], acc[mi][ni+2], 0, 0, 0);
      __builtin_amdgcn_s_setprio(0);
      LGKM0();
      SBAR();

      // ---- ph3: 8 ds_reads (afB); stage B(t+2); MFMA Q(4-7, 0-1)
      #pragma unroll
      for (int mi = 0; mi < 4; mi++)
        #pragma unroll
        for (int kk = 0; kk < 2; kk++)
          afB[mi][kk] = *(const short8*)(Ab + (wr + (mi+4)*16 + lr) * 64 + (((kk<<2) + lq) ^ r7) * 8);
      if (st) {
        #pragma unroll
        for (int i = 0; i < 4; i++) ASYNC_LD16(gB0 + i * sB64 + kt2, lB0 + i * 4096 + cb);
      }
      __builtin_amdgcn_s_setprio(1);
      #pragma unroll
      for (int mi = 0; mi < 4; mi++)
        #pragma unroll
        for (int ni = 0; ni < 2; ni++)
          #pragma unroll
          for (int kk = 0; kk < 2; kk++)
            acc[mi+4][ni] = MFMA_BF16(afB[mi][kk], bf01[ni][kk], acc[mi+4][ni], 0, 0, 0);
      __builtin_amdgcn_s_setprio(0);
      LGKM0();
      SBAR();

      // ---- ph4: stage A(t+2); MFMA Q(4-7, 2-3); boundary
      if (st) {
        #pragma unroll
        for (int i = 0; i < 4; i++) ASYNC_LD16(gA0 + i * sA64 + kt2, lA0 + i * 4096 + cb);
      }
      __builtin_amdgcn_s_setprio(1);
      #pragma unroll
      for (int mi = 0; mi < 4; mi++)
        #pragma unroll
        for (int ni = 0; ni < 2; ni++)
          #pragma unroll
          for (int kk = 0; kk < 2; kk++)
            acc[mi+4][ni+2] = MFMA_BF16(afB[mi][kk], bf23[ni][kk], acc[mi+4][ni+2], 0, 0, 0);
      __builtin_amdgcn_s_setprio(0);
      if (st) { asm volatile("s_waitcnt vmcnt(8)" ::: "memory"); }
      else    { asm volatile("s_waitcnt vmcnt(0)" ::: "memory"); }
      SBAR();
    }

    // epilogue: u (sigmoid, bf16) for gn<1024 else r (silu)
    #pragma unroll
    for (int mi = 0; mi < 8; mi++)
      #pragma unroll
      for (int ni = 0; ni < 4; ni++)
        #pragma unroll
        for (int r = 0; r < 4; r++) {
          const int gm = row0 + wr + mi * 16 + lq * 4 + r;
          const int gn = col0 + wc + ni * 16 + lr;
          float v = acc[mi][ni][r] + bq[gn];
          if (gn < 1024) {
            ((unsigned short*)ub_f)[(long long)gm * 1024 + gn] = f2u(sigmoidf_(v));
          } else {
            rbf[(long long)gm * 1024 + (gn - 1024)] = f2u(siluf_(v));
          }
        }
  } else {
    // ================= 256x128 2-phase counted-vmcnt body (R4-exact) =================
    // decode: g2 (256 blocks) or proj (64 blocks: z=0 q-slice, z=1 k-proj)
    const unsigned short* Ag; const unsigned short* Bg;
    int row0, col0, zproj = -1;
    if (bid < 512) {
      const int idx = bid - 256;          // g2: grid (4,64)
      row0 = (idx & 3) * 256;             // e-rows of Wv
      col0 = (idx >> 2) * 128;            // (b,s) cols
      Ag = Wvb; Bg = kbr;
    } else {
      const int idx = bid - 512;          // proj: 64 blocks
      zproj = idx >> 5;                   // 0: q-slice, 1: k-proj
      row0 = (idx & 31) * 256;            // M=8192
      col0 = 0;                           // N=128
      Ag = zproj ? kbr : qbf;
      Bg = zproj ? Wkb : (Wqb + 2048LL * 1024);
    }
    const int lda = 1024, ldb = 1024;
    const int wr = (wv & 3) * 64;
    const int wc = (wv >> 2) * 64;

    const int rr0 = tid >> 3;
    const int swz = ((tid & 7) ^ (rr0 & 7)) * 8;
    const unsigned short* gA0 = Ag + (long long)(row0 + rr0) * lda + swz;
    const unsigned short* gB0 = Bg + (long long)(col0 + rr0) * ldb + swz;
    const long long sA64 = 64LL * lda, sB64 = 64LL * ldb;
    unsigned short* lA0 = &Ls[0]     + tid * 8;
    unsigned short* lB0 = &Ls[16384] + tid * 8;

    floatx4 acc[4][4];
    #pragma unroll
    for (int i = 0; i < 4; i++)
      #pragma unroll
      for (int j = 0; j < 4; j++) acc[i][j] = zero;

    const int NT = 16; // K=1024

    #pragma unroll
    for (int i = 0; i < 4; i++) ASYNC_LD16(gA0 + i * sA64,      lA0 + i * 4096);
    #pragma unroll
    for (int i = 0; i < 2; i++) ASYNC_LD16(gB0 + i * sB64,      lB0 + i * 4096);
    #pragma unroll
    for (int i = 0; i < 4; i++) ASYNC_LD16(gA0 + i * sA64 + 64, lA0 + i * 4096 + 24576);
    #pragma unroll
    for (int i = 0; i < 2; i++) ASYNC_LD16(gB0 + i * sB64 + 64, lB0 + i * 4096 + 24576);
    asm volatile("s_waitcnt vmcnt(6)" ::: "memory");
    SBAR();

    for (int t = 0; t < NT; ++t) {
      const int cb = (t & 1) * 24576;
      const unsigned short* Ab = &Ls[cb];
      const unsigned short* Bb = &Ls[cb + 16384];
      const bool st = (t + 2) < NT;
      const int kt2 = (t + 2) << 6;

      short8 afA[4][2], bfv[4][2];

      // ---- phase 1: all 16 ds_reads; lgkm-gate; 16 MFMA (ni0-1)
      #pragma unroll
      for (int mi = 0; mi < 4; mi++)
        #pragma unroll
        for (int kk = 0; kk < 2; kk++)
          afA[mi][kk] = *(const short8*)(Ab + (wr + mi*16 + lr) * 64 + (((kk<<2) + lq) ^ r7) * 8);
      #pragma unroll
      for (int ni = 0; ni < 4; ni++)
        #pragma unroll
        for (int kk = 0; kk < 2; kk++)
          bfv[ni][kk] = *(const short8*)(Bb + (wc + ni*16 + lr) * 64 + (((kk<<2) + lq) ^ r7) * 8);
      LGKM0();
      __builtin_amdgcn_sched_barrier(0);
      __builtin_amdgcn_s_setprio(1);
      #pragma unroll
      for (int mi = 0; mi < 4; mi++)
        #pragma unroll
        for (int ni = 0; ni < 2; ni++)
          #pragma unroll
          for (int kk = 0; kk < 2; kk++)
            acc[mi][ni] = MFMA_BF16(afA[mi][kk], bfv[ni][kk], acc[mi][ni], 0, 0, 0);
      __builtin_amdgcn_s_setprio(0);
      SBAR();   // all waves' reads of tile t complete -> buffer slots free

      // ---- phase 2: stage t+2 (same-parity buffer); 16 MFMA (ni2-3, regs)
      if (st) {
        #pragma unroll
        for (int i = 0; i < 4; i++) ASYNC_LD16(gA0 + i * sA64 + kt2, lA0 + i * 4096 + cb);
        #pragma unroll
        for (int i = 0; i < 2; i++) ASYNC_LD16(gB0 + i * sB64 + kt2, lB0 + i * 4096 + cb);
      }
      __builtin_amdgcn_s_setprio(1);
      #pragma unroll
      for (int mi = 0; mi < 4; mi++)
        #pragma unroll
        for (int ni = 0; ni < 2; ni++)
          #pragma unroll
          for (int kk = 0; kk < 2; kk++)
            acc[mi][ni+2] = MFMA_BF16(afA[mi][kk], bfv[ni+2][kk], acc[mi][ni+2], 0, 0, 0);
      __builtin_amdgcn_s_setprio(0);
      if (st) { asm volatile("s_waitcnt vmcnt(6)" ::: "memory"); }
      else    { asm volatile("s_waitcnt vmcnt(0)" ::: "memory"); }
      SBAR();
    }

    // epilogues
    if (zproj < 0) {
      // g2: vT[b][e][s] = silu(v + bv[e]), coalesced along s
      #pragma unroll
      for (int mi = 0; mi < 4; mi++)
        #pragma unroll
        for (int ni = 0; ni < 4; ni++)
          #pragma unroll
          for (int r = 0; r < 4; r++) {
            const int gm = row0 + wr + mi * 16 + lq * 4 + r;
            const int gn = col0 + wc + ni * 16 + lr;
            const float v = acc[mi][ni][r] + bv[gm];
            const int b = gn >> 11, s = gn & 2047;
            vT[((long long)b * 1024 + gm) * 2048 + s] = f2u(siluf_(v));
          }
    } else {
      const float* bias = zproj ? bk : (bq + 2048);
      const float* gam  = zproj ? (gamma + 128) : gamma;
      const float* bet  = zproj ? (beta + 128)  : beta;
      unsigned short* ob = zproj ? kpj : qpj;
      #pragma unroll
      for (int mi = 0; mi < 4; mi++)
        #pragma unroll
        for (int ni = 0; ni < 4; ni++)
          #pragma unroll
          for (int r = 0; r < 4; r++) {
            const int gm = row0 + wr + mi * 16 + lq * 4 + r;
            const int gn = wc + ni * 16 + lr;
            const float v = acc[mi][ni][r] + bias[gn];
            ob[(long long)gm * 128 + gn] = f2u(siluf_(v) * gam[gn] + bet[gn]);
          }
    }
  }
}

// ---------------------------------------------------------------- 256x128 counted-vmcnt GEMM (g5, R4-exact)
__global__ __launch_bounds__(512, 2)
void gemm_g5(const unsigned short* __restrict__ A, int lda,
             const unsigned short* __restrict__ Bm, int ldb,
             int K,
             const float* __restrict__ bias,
             float* __restrict__ f0,
             const unsigned short* __restrict__ rmul,
             const float* __restrict__ qin)
{
  __shared__ __align__(16) unsigned short Ls[49152]; // 96 KiB

  const int tid = threadIdx.x;
  const int bm = blockIdx.x, bn = blockIdx.y;
  const int row0 = bm * 256;
  const int col0 = bn * 128;

  const int lane = tid & 63;
  const int wv   = tid >> 6;
  const int wr   = (wv & 3) * 64;
  const int wc   = (wv >> 2) * 64;
  const int lr   = lane & 15;
  const int lq   = lane >> 4;
  const int r7   = lr & 7;

  const int rr0 = tid >> 3;
  const int swz = ((tid & 7) ^ (rr0 & 7)) * 8;
  const unsigned short* gA0 = A  + (long long)(row0 + rr0) * lda + swz;
  const unsigned short* gB0 = Bm + (long long)(col0 + rr0) * ldb + swz;
  const long long sA64 = 64LL * lda, sB64 = 64LL * ldb;
  unsigned short* lA0 = &Ls[0]     + tid * 8;
  unsigned short* lB0 = &Ls[16384] + tid * 8;

  floatx4 acc[4][4];
  const floatx4 zero = {0.f, 0.f, 0.f, 0.f};
  #pragma unroll
  for (int i = 0; i < 4; i++)
    #pragma unroll
    for (int j = 0; j < 4; j++) acc[i][j] = zero;

  const int NT = K >> 6;

  #pragma unroll
  for (int i = 0; i < 4; i++) ASYNC_LD16(gA0 + i * sA64,      lA0 + i * 4096);
  #pragma unroll
  for (int i = 0; i < 2; i++) ASYNC_LD16(gB0 + i * sB64,      lB0 + i * 4096);
  #pragma unroll
  for (int i = 0; i < 4; i++) ASYNC_LD16(gA0 + i * sA64 + 64, lA0 + i * 4096 + 24576);
  #pragma unroll
  for (int i = 0; i < 2; i++) ASYNC_LD16(gB0 + i * sB64 + 64, lB0 + i * 4096 + 24576);
  asm volatile("s_waitcnt vmcnt(6)" ::: "memory");
  SBAR();

  for (int t = 0; t < NT; ++t) {
    const int cb = (t & 1) * 24576;
    const unsigned short* Ab = &Ls[cb];
    const unsigned short* Bb = &Ls[cb + 16384];
    const bool st = (t + 2) < NT;
    const int kt2 = (t + 2) << 6;

    short8 afA[4][2], bfv[4][2];

    #pragma unroll
    for (int mi = 0; mi < 4; mi++)
      #pragma unroll
      for (int kk = 0; kk < 2; kk++)
        afA[mi][kk] = *(const short8*)(Ab + (wr + mi*16 + lr) * 64 + (((kk<<2) + lq) ^ r7) * 8);
    #pragma unroll
    for (int ni = 0; ni < 4; ni++)
      #pragma unroll
      for (int kk = 0; kk < 2; kk++)
        bfv[ni][kk] = *(const short8*)(Bb + (wc + ni*16 + lr) * 64 + (((kk<<2) + lq) ^ r7) * 8);
    LGKM0();
    __builtin_amdgcn_sched_barrier(0);
    __builtin_amdgcn_s_setprio(1);
    #pragma unroll
    for (int mi = 0; mi < 4; mi++)
      #pragma unroll
      for (int ni = 0; ni < 2; ni++)
        #pragma unroll
        for (int kk = 0; kk < 2; kk++)
          acc[mi][ni] = MFMA_BF16(afA[mi][kk], bfv[ni][kk], acc[mi][ni], 0, 0, 0);
    __builtin_amdgcn_s_setprio(0);
    SBAR();

    if (st) {
      #pragma unroll
      for (int i = 0; i < 4; i++) ASYNC_LD16(gA0 + i * sA64 + kt2, lA0 + i * 4096 + cb);
      #pragma unroll
      for (int i = 0; i < 2; i++) ASYNC_LD16(gB0 + i * sB64 + kt2, lB0 + i * 4096 + cb);
    }
    __builtin_amdgcn_s_setprio(1);
    #pragma unroll
    for (int mi = 0; mi < 4; mi++)
      #pragma unroll
      for (int ni = 0; ni < 2; ni++)
        #pragma unroll
        for (int kk = 0; kk < 2; kk++)
          acc[mi][ni+2] = MFMA_BF16(afA[mi][kk], bfv[ni+2][kk], acc[mi][ni+2], 0, 0, 0);
    __builtin_amdgcn_s_setprio(0);
    if (st) { asm volatile("s_waitcnt vmcnt(6)" ::: "memory"); }
    else    { asm volatile("s_waitcnt vmcnt(0)" ::: "memory"); }
    SBAR();
  }

  #pragma unroll
  for (int mi = 0; mi < 4; mi++)
    #pragma unroll
    for (int ni = 0; ni < 4; ni++)
      #pragma unroll
      for (int r = 0; r < 4; r++) {
        const int gm = row0 + wr + mi * 16 + lq * 4 + r;
        const int gn = col0 + wc + ni * 16 + lr;
        const long long idx = (long long)gm * 1024 + gn;
        const float tv = tanhf(acc[mi][ni][r] + bias[gn]);
        const float qv = qin[idx];
        f0[idx] = qv + u2f(rmul[idx]) * (tv - qv);
      }
}

// ---------------------------------------------------------------- fused attention (R7-exact, 75us measured)
__global__ __launch_bounds__(512, 2)
void attn_fused(const unsigned short* __restrict__ qpj,  // (T,B,Z)
                const unsigned short* __restrict__ kpj,  // [B][S][Z]
                const unsigned short* __restrict__ vT,   // [B][E][S]
                const unsigned short* __restrict__ rbf,  // (T*B, E)
                unsigned short* __restrict__ hrb)        // (T*B, E) = h*r
{
  __shared__ __align__(16) unsigned short Vs[32768];     // 512 e-rows x 64 s
  __shared__ __align__(16) unsigned short Ks[2][8192];   // 64 s-rows x 128 Z dbuf
  __shared__ __align__(16) unsigned short Ps[4096];      // 64 t x 64 s
  __shared__ float rsl[64];

  const int tid = threadIdx.x;
  const int eh = blockIdx.x, ty = blockIdx.y, bz = blockIdx.z;
  const int t0 = ty * 64;

  const int lane = tid & 63;
  const int wv   = tid >> 6;
  const int lr   = lane & 15;
  const int lq   = lane >> 4;
  const int mi_s = wv & 3;
  const int niA  = (wv >> 2) * 2;

  const unsigned short* kb_g = kpj + (long long)bz * 2048 * 128;
  const unsigned short* vb_g = vT  + (long long)bz * 1024 * 2048;

  short8 afq[4];
  {
    const unsigned short* qrow = qpj + (long long)bz * 128
                               + (long long)(t0 + mi_s * 16 + lr) * 512;
    #pragma unroll
    for (int kd = 0; kd < 4; kd++)
      afq[kd] = *(const short8*)(qrow + (kd * 4 + lq) * 8);
  }

  const int rrV = tid >> 3;
  const int gcV = ((tid & 7) ^ (rrV & 7)) * 8;
  const unsigned short* gV0 = vb_g + (long long)(eh * 512 + rrV) * 2048 + gcV;
  unsigned short* lV0 = Vs + tid * 8;
  const int rrK = tid >> 4;
  const int gcK = ((tid & 15) ^ (rrK & 15)) * 8;
  const unsigned short* gK0 = kb_g + (long long)rrK * 128 + gcK;
  unsigned short* lK0 = &Ks[0][0] + tid * 8;

  floatx4 acc[4][4];
  floatx4 accSum[4];
  const floatx4 zero = {0.f, 0.f, 0.f, 0.f};
  #pragma unroll
  for (int i = 0; i < 4; i++) {
    accSum[i] = zero;
    #pragma unroll
    for (int j = 0; j < 4; j++) acc[i][j] = zero;
  }
  const short ob = (short)0x3F80;
  const short8 ones = {ob, ob, ob, ob, ob, ob, ob, ob};

  #pragma unroll
  for (int i = 0; i < 2; i++) ASYNC_LD16(gK0 + i * 4096, lK0 + i * 4096);

  for (int t = 0; t < 32; ++t) {
    const unsigned short* Kb = &Ks[t & 1][0];
    const bool st = (t + 1) < 32;

    #pragma unroll
    for (int i = 0; i < 8; i++)
      ASYNC_LD16(gV0 + (long long)i * 131072 + t * 64, lV0 + i * 4096);
    if (st) {
      unsigned short* lKn = &Ks[(t + 1) & 1][0] + tid * 8;
      #pragma unroll
      for (int i = 0; i < 2; i++)
        ASYNC_LD16(gK0 + (long long)(t + 1) * 8192 + i * 4096, lKn + i * 4096);
    }
    if (st) { asm volatile("s_waitcnt vmcnt(10)" ::: "memory"); }
    else    { asm volatile("s_waitcnt vmcnt(8)"  ::: "memory"); }
    SBAR();

    floatx4 accS[2] = {zero, zero};
    short8 bfk[2][4];
    #pragma unroll
    for (int f = 0; f < 2; f++)
      #pragma unroll
      for (int kd = 0; kd < 4; kd++)
        bfk[f][kd] = *(const short8*)(Kb + ((niA + f) * 16 + lr) * 128
                                         + (((kd * 4 + lq) ^ lr) & 15) * 8);
    #pragma unroll
    for (int f = 0; f < 2; f++)
      #pragma unroll
      for (int kd = 0; kd < 4; kd++)
        accS[f] = MFMA_BF16(afq[kd], bfk[f][kd], accS[f], 0, 0, 0);
    #pragma unroll
    for (int f = 0; f < 2; f++) {
      const int nif = niA + f;
      #pragma unroll
      for (int r = 0; r < 4; r++) {
        const float e = __expf(accS[f][r] * SCALING);
        const int trow = mi_s * 16 + lq * 4 + r;
        const int scol = nif * 16 + lr;
        const int slot = (scol >> 3) ^ (trow & 7);
        Ps[trow * 64 + slot * 8 + (lr & 7)] = f2u(e);
      }
    }
    LGKM0();
    if (st) { asm volatile("s_waitcnt vmcnt(2)" ::: "memory"); }
    else    { asm volatile("s_waitcnt vmcnt(0)" ::: "memory"); }
    SBAR();

    short8 afP[4][2], bfv[4][2];
    #pragma unroll
    for (int mi = 0; mi < 4; mi++)
      #pragma unroll
      for (int k8 = 0; k8 < 2; k8++)
        afP[mi][k8] = *(const short8*)(Ps + (mi * 16 + lr) * 64
                                          + ((k8 * 4 + lq) ^ (lr & 7)) * 8);
    #pragma unroll
    for (int ni = 0; ni < 4; ni++)
      #pragma unroll
      for (int k8 = 0; k8 < 2; k8++)
        bfv[ni][k8] = *(const short8*)(Vs + (wv * 64 + ni * 16 + lr) * 64
                                          + ((k8 * 4 + lq) ^ (lr & 7)) * 8);
    __builtin_amdgcn_s_setprio(1);
    #pragma unroll
    for (int mi = 0; mi < 4; mi++)
      #pragma unroll
      for (int ni = 0; ni < 4; ni++)
        #pragma unroll
        for (int k8 = 0; k8 < 2; k8++)
          acc[mi][ni] = MFMA_BF16(afP[mi][k8], bfv[ni][k8], acc[mi][ni], 0, 0, 0);
    __builtin_amdgcn_s_setprio(0);
    if (wv == 0) {
      #pragma unroll
      for (int mi = 0; mi < 4; mi++)
        #pragma unroll
        for (int k8 = 0; k8 < 2; k8++)
          accSum[mi] = MFMA_BF16(afP[mi][k8], ones, accSum[mi], 0, 0, 0);
    }
    LGKM0();
    SBAR();
  }

  if (wv == 0 && lr == 0) {
    #pragma unroll
    for (int mi = 0; mi < 4; mi++)
      #pragma unroll
      for (int r = 0; r < 4; r++)
        rsl[mi * 16 + lq * 4 + r] = accSum[mi][r];
  }
  LGKM0();
  SBAR();
  #pragma unroll
  for (int mi = 0; mi < 4; mi++) {
    float iv[4];
    #pragma unroll
    for (int r = 0; r < 4; r++) iv[r] = 1.0f / rsl[mi * 16 + lq * 4 + r];
    #pragma unroll
    for (int ni = 0; ni < 4; ni++) {
      #pragma unroll
      for (int r = 0; r < 4; r++) {
        const int gt = t0 + mi * 16 + lq * 4 + r;
        const int ge = eh * 512 + wv * 64 + ni * 16 + lr;
        const long long idx = ((long long)gt * 4 + bz) * 1024 + ge;
        hrb[idx] = f2u(acc[mi][ni][r] * iv[r] * u2f(rbf[idx]));
      }
    }
  }
}

// ---------------------------------------------------------------- launch
extern "C" void kernel_launch(void* const* d_in, const int* in_sizes, int n_in,
                              void* d_out, int out_size, void* d_ws, size_t ws_size,
                              hipStream_t stream)
{
  (void)in_sizes; (void)n_in; (void)out_size; (void)ws_size;
  const float* query = (const float*)d_in[0];
  const float* key   = (const float*)d_in[1];
  const float* Wq    = (const float*)d_in[2];
  const float* bq    = (const float*)d_in[3];
  const float* Wk    = (const float*)d_in[4];
  const float* bk    = (const float*)d_in[5];
  const float* Wv    = (const float*)d_in[6];
  const float* bv    = (const float*)d_in[7];
  const float* Wh    = (const float*)d_in[8];
  const float* bh    = (const float*)d_in[9];
  const float* gamma = (const float*)d_in[10];
  const float* beta  = (const float*)d_in[11];
  float* out = (float*)d_out;

  char* p = (char*)d_ws;
  auto take = [&](size_t bytes) -> char* {
    char* r = p; p += (bytes + 255) & ~(size_t)255; return r;
  };
  unsigned short* qbf = (unsigned short*)take(8192ULL * 1024 * 2); // query bf16 (T*B,E)
  unsigned short* kbr = (unsigned short*)take(8192ULL * 1024 * 2); // key bf16 [B][S][E]
  unsigned short* Wqb = (unsigned short*)take(2176ULL * 1024 * 2);
  unsigned short* Wkb = (unsigned short*)take(128ULL  * 1024 * 2);
  unsigned short* Wvb = (unsigned short*)take(1024ULL * 1024 * 2);
  unsigned short* Whb = (unsigned short*)take(1024ULL * 1024 * 2);
  unsigned short* ub  = (unsigned short*)take(8192ULL * 1024 * 2); // u gate bf16
  unsigned short* rbf = (unsigned short*)take(8192ULL * 1024 * 2); // r bf16
  unsigned short* qpj = (unsigned short*)take(8192ULL * 128 * 2);  // q (T,B,Z)
  unsigned short* kpj = (unsigned short*)take(8192ULL * 128 * 2);  // k [B][S][Z]
  unsigned short* vT  = (unsigned short*)take(4ULL * 1024 * 2048 * 2); // v^T [B][E][S]
  unsigned short* hrb = (unsigned short*)take(8192ULL * 1024 * 2); // h*r bf16

  dim3 blk(256);
  dim3 gblk(512);
  // 1: all casts, one dispatch
  cast_all<<<20736, blk, 0, stream>>>(query, key, Wq, Wk, Wv, Wh,
      qbf, kbr, Wqb, Wkb, Wvb, Whb);
  // 2: g0 + g2 + both N=128 projections, one dispatch (576 blocks)
  mega<<<576, gblk, 0, stream>>>(qbf, Wqb, kbr, Wvb, Wkb,
      bq, bk, bv, gamma, beta, (float*)ub, rbf, vT, qpj, kpj);
  // 3: fused attention: hr = softmax(q k^T * scale) @ V * r
  attn_fused<<<dim3(2, 32, 4), gblk, 0, stream>>>(qpj, kpj, vT, rbf, hrb);
  // 4: out = query + u * (tanh(hr @ Wh^T + bh) - query)
  gemm_g5<<<dim3(32, 8, 1), gblk, 0, stream>>>(hrb, 1024, Whb, 1024, 1024,
      bh, out, ub, query);
}

// Round 11
// 331.176 us; speedup vs baseline: 1.8841x; 1.0020x over previous
//
#include <hip/hip_runtime.h>
#include <cstdint>
#include <cstddef>

using short8  = __attribute__((ext_vector_type(8))) short;
using floatx4 = __attribute__((ext_vector_type(4))) float;

#define DEV __device__ __forceinline__

DEV float u2f(unsigned short u){
  union { unsigned int i; float f; } c; c.i = ((unsigned int)u) << 16; return c.f;
}
DEV unsigned short f2u(float f){
  union { float f; unsigned int i; } c; c.f = f;
  unsigned int i = c.i;
  i += 0x7fffu + ((i >> 16) & 1u);   // RNE to bf16 (finite values only here)
  return (unsigned short)(i >> 16);
}
DEV float sigmoidf_(float x){ return 1.0f / (1.0f + __expf(-x)); }
DEV float siluf_(float x){ return x / (1.0f + __expf(-x)); }

// async global->LDS, 16 B per lane; LDS dest must be wave-uniform base + lane*16
#define ASYNC_LD16(g, l) __builtin_amdgcn_global_load_lds( \
    (const __attribute__((address_space(1))) unsigned int*)(g), \
    (__attribute__((address_space(3))) unsigned int*)(l), 16, 0, 0)

#define MFMA_BF16 __builtin_amdgcn_mfma_f32_16x16x32_bf16

// raw barrier, opaque to the compiler's waitcnt-insertion pass: no implicit
// vmcnt(0) drain can be attached (R3-proven: 122us -> 53.8us on gemm256).
#define SBAR() asm volatile("s_barrier" ::: "memory")
#define LGKM0() asm volatile("s_waitcnt lgkmcnt(0)" ::: "memory")

// problem-fixed sizes: T=2048 S=2048 B=4 E=1024 Z=128
constexpr float SCALING = 0.088388347648318447f; // 128^-0.5

// ---------------------------------------------------------------- fused casts
// 512 thr = 2 rows/block. Row r: [0,8192) query -> qbf; [8192,16384) key -> kbr
// (batch de-interleave); [16384,18560) Wq; [18560,18688) Wk; [18688,19712) Wv;
// [19712,20736) Wh.
__global__ __launch_bounds__(512) void cast_all(
    const float* __restrict__ q, const float* __restrict__ k,
    const float* __restrict__ Wq, const float* __restrict__ Wk,
    const float* __restrict__ Wv, const float* __restrict__ Wh,
    unsigned short* __restrict__ qo, unsigned short* __restrict__ ko,
    unsigned short* __restrict__ oq, unsigned short* __restrict__ ok,
    unsigned short* __restrict__ ov, unsigned short* __restrict__ oh)
{
  const int r = blockIdx.x * 2 + (threadIdx.x >> 8);
  const int e = (threadIdx.x & 255) * 4;
  const float* src; unsigned short* dst;
  if (r < 8192) {
    src = q + (long long)r * 1024;
    dst = qo + (long long)r * 1024;
  } else if (r < 16384) {
    const int m = r - 8192;
    const int s = m >> 2, b = m & 3;
    src = k + (long long)m * 1024;
    dst = ko + ((long long)b * 2048 + s) * 1024;
  } else if (r < 18560) { src = Wq + (long long)(r-16384) * 1024; dst = oq + (long long)(r-16384) * 1024; }
  else if (r < 18688)   { src = Wk + (long long)(r-18560) * 1024; dst = ok + (long long)(r-18560) * 1024; }
  else if (r < 19712)   { src = Wv + (long long)(r-18688) * 1024; dst = ov + (long long)(r-18688) * 1024; }
  else                  { src = Wh + (long long)(r-19712) * 1024; dst = oh + (long long)(r-19712) * 1024; }
  const float4 v = *(const float4*)(src + e);
  ushort4 o; o.x=f2u(v.x); o.y=f2u(v.y); o.z=f2u(v.z); o.w=f2u(v.w);
  *(ushort4*)(dst + e) = o;
}

// ---------------------------------------------------------------- MEGA dispatch
// 576 blocks x 512 thr, one 128K LDS pool (all paths were 1 block/CU anyway).
// bid <256 : g0  = gemm256 body (R5-proven): Wq-main -> u, r
// bid <512 : g2  = gemm_n128<2> body (R4-proven): vT = silu(Wv @ kbr^T + bv)
// bid <576 : proj = same 2-phase 256x128 body, EPI1 epilogue:
//            z=0 q-slice (Wq rows 2048..2175) -> qpj ; z=1 k-proj -> kpj
// Heavy blocks first: light proj blocks tail-fill CUs as g0 blocks retire.
// Packing floor: total-work/256CU = 51+27+6.75 ~ 85us; measured 94 (90% eff).
__global__ __launch_bounds__(512, 2)
void mega(const unsigned short* __restrict__ qbf,
          const unsigned short* __restrict__ Wqb,
          const unsigned short* __restrict__ kbr,
          const unsigned short* __restrict__ Wvb,
          const unsigned short* __restrict__ Wkb,
          const float* __restrict__ bq, const float* __restrict__ bk,
          const float* __restrict__ bv,
          const float* __restrict__ gamma, const float* __restrict__ beta,
          float* __restrict__ ub_f,          // u gate (bf16 via reinterpret)
          unsigned short* __restrict__ rbf,  // r
          unsigned short* __restrict__ vT,   // [B][E][S]
          unsigned short* __restrict__ qpj,  // (T,B,Z)
          unsigned short* __restrict__ kpj)  // [B][S][Z]
{
  __shared__ __align__(16) unsigned short Ls[65536]; // 128 KiB

  const int bid = blockIdx.x;
  const int tid = threadIdx.x;
  const int lane = tid & 63;
  const int wv   = tid >> 6;
  const int lr   = lane & 15;
  const int lq   = lane >> 4;
  const int r7   = lr & 7;

  const floatx4 zero = {0.f, 0.f, 0.f, 0.f};

  if (bid < 256) {
    // ================= g0: 256x256 counted-vmcnt GEMM (R5-exact body) =================
    const int bm = bid & 31, bn = bid >> 5;
    const int row0 = bm * 256;
    const int col0 = bn * 256;
    const int lda = 1024, ldb = 1024;
    const int wr = (wv >> 2) * 128;
    const int wc = (wv & 3) * 64;

    const int rr0 = tid >> 3;
    const int swz = ((tid & 7) ^ (rr0 & 7)) * 8;
    const unsigned short* gA0 = qbf + (long long)(row0 + rr0) * lda + swz;
    const unsigned short* gB0 = Wqb + (long long)(col0 + rr0) * ldb + swz;
    const long long sA64 = 64LL * lda, sB64 = 64LL * ldb;
    unsigned short* lA0 = &Ls[0]     + tid * 8;
    unsigned short* lB0 = &Ls[16384] + tid * 8;

    floatx4 acc[8][4];
    #pragma unroll
    for (int i = 0; i < 8; i++)
      #pragma unroll
      for (int j = 0; j < 4; j++) acc[i][j] = zero;

    const int NT = 16; // K=1024

    #pragma unroll
    for (int i = 0; i < 4; i++) ASYNC_LD16(gA0 + i * sA64,      lA0 + i * 4096);
    #pragma unroll
    for (int i = 0; i < 4; i++) ASYNC_LD16(gB0 + i * sB64,      lB0 + i * 4096);
    #pragma unroll
    for (int i = 0; i < 4; i++) ASYNC_LD16(gA0 + i * sA64 + 64, lA0 + i * 4096 + 32768);
    #pragma unroll
    for (int i = 0; i < 4; i++) ASYNC_LD16(gB0 + i * sB64 + 64, lB0 + i * 4096 + 32768);
    asm volatile("s_waitcnt vmcnt(8)" ::: "memory");
    SBAR();

    for (int t = 0; t < NT; ++t) {
      const int cb = (t & 1) << 15;
      const unsigned short* Ab = &Ls[cb];
      const unsigned short* Bb = &Ls[cb + 16384];
      const bool st = (t + 2) < NT;
      const int kt2 = (t + 2) << 6;

      short8 afA[4][2], afB[4][2], bf01[2][2], bf23[2][2];

      // ---- ph1+ph2 (fused): 16 ds_reads; 32 MFMA Q(0-3, 0-3)
      #pragma unroll
      for (int mi = 0; mi < 4; mi++)
        #pragma unroll
        for (int kk = 0; kk < 2; kk++)
          afA[mi][kk] = *(const short8*)(Ab + (wr + mi*16 + lr) * 64 + (((kk<<2) + lq) ^ r7) * 8);
      #pragma unroll
      for (int ni = 0; ni < 2; ni++)
        #pragma unroll
        for (int kk = 0; kk < 2; kk++)
          bf01[ni][kk] = *(const short8*)(Bb + (wc + ni*16 + lr) * 64 + (((kk<<2) + lq) ^ r7) * 8);
      #pragma unroll
      for (int ni = 0; ni < 2; ni++)
        #pragma unroll
        for (int kk = 0; kk < 2; kk++)
          bf23[ni][kk] = *(const short8*)(Bb + (wc + (ni+2)*16 + lr) * 64 + (((kk<<2) + lq) ^ r7) * 8);
      __builtin_amdgcn_s_setprio(1);
      #pragma unroll
      for (int mi = 0; mi < 4; mi++)
        #pragma unroll
        for (int ni = 0; ni < 2; ni++)
          #pragma unroll
          for (int kk = 0; kk < 2; kk++)
            acc[mi][ni] = MFMA_BF16(afA[mi][kk], bf01[ni][kk], acc[mi][ni], 0, 0, 0);
      #pragma unroll
      for (int mi = 0; mi < 4; mi++)
        #pragma unroll
        for (int ni = 0; ni < 2; ni++)
          #pragma unroll
          for (int kk = 0; kk < 2; kk++)
            acc[mi][ni+2] = MFMA_BF16(afA[mi][kk], bf23[ni][kk], acc[mi][ni+2], 0, 0, 0);
      __builtin_amdgcn_s_setprio(0);
      LGKM0();
      SBAR();

      // ---- ph3: 8 ds_reads (afB); stage B(t+2); MFMA Q(4-7, 0-1)
      #pragma unroll
      for (int mi = 0; mi < 4; mi++)
        #pragma unroll
        for (int kk = 0; kk < 2; kk++)
          afB[mi][kk] = *(const short8*)(Ab + (wr + (mi+4)*16 + lr) * 64 + (((kk<<2) + lq) ^ r7) * 8);
      if (st) {
        #pragma unroll
        for (int i = 0; i < 4; i++) ASYNC_LD16(gB0 + i * sB64 + kt2, lB0 + i * 4096 + cb);
      }
      __builtin_amdgcn_s_setprio(1);
      #pragma unroll
      for (int mi = 0; mi < 4; mi++)
        #pragma unroll
        for (int ni = 0; ni < 2; ni++)
          #pragma unroll
          for (int kk = 0; kk < 2; kk++)
            acc[mi+4][ni] = MFMA_BF16(afB[mi][kk], bf01[ni][kk], acc[mi+4][ni], 0, 0, 0);
      __builtin_amdgcn_s_setprio(0);
      LGKM0();
      SBAR();

      // ---- ph4: stage A(t+2); MFMA Q(4-7, 2-3); boundary
      if (st) {
        #pragma unroll
        for (int i = 0; i < 4; i++) ASYNC_LD16(gA0 + i * sA64 + kt2, lA0 + i * 4096 + cb);
      }
      __builtin_amdgcn_s_setprio(1);
      #pragma unroll
      for (int mi = 0; mi < 4; mi++)
        #pragma unroll
        for (int ni = 0; ni < 2; ni++)
          #pragma unroll
          for (int kk = 0; kk < 2; kk++)
            acc[mi+4][ni+2] = MFMA_BF16(afB[mi][kk], bf23[ni][kk], acc[mi+4][ni+2], 0, 0, 0);
      __builtin_amdgcn_s_setprio(0);
      if (st) { asm volatile("s_waitcnt vmcnt(8)" ::: "memory"); }
      else    { asm volatile("s_waitcnt vmcnt(0)" ::: "memory"); }
      SBAR();
    }

    // epilogue: u (sigmoid, bf16) for gn<1024 else r (silu)
    #pragma unroll
    for (int mi = 0; mi < 8; mi++)
      #pragma unroll
      for (int ni = 0; ni < 4; ni++)
        #pragma unroll
        for (int r = 0; r < 4; r++) {
          const int gm = row0 + wr + mi * 16 + lq * 4 + r;
          const int gn = col0 + wc + ni * 16 + lr;
          float v = acc[mi][ni][r] + bq[gn];
          if (gn < 1024) {
            ((unsigned short*)ub_f)[(long long)gm * 1024 + gn] = f2u(sigmoidf_(v));
          } else {
            rbf[(long long)gm * 1024 + (gn - 1024)] = f2u(siluf_(v));
          }
        }
  } else {
    // ================= 256x128 2-phase counted-vmcnt body (R4-exact) =================
    // decode: g2 (256 blocks) or proj (64 blocks: z=0 q-slice, z=1 k-proj)
    const unsigned short* Ag; const unsigned short* Bg;
    int row0, col0, zproj = -1;
    if (bid < 512) {
      const int idx = bid - 256;          // g2: grid (4,64)
      row0 = (idx & 3) * 256;             // e-rows of Wv
      col0 = (idx >> 2) * 128;            // (b,s) cols
      Ag = Wvb; Bg = kbr;
    } else {
      const int idx = bid - 512;          // proj: 64 blocks
      zproj = idx >> 5;                   // 0: q-slice, 1: k-proj
      row0 = (idx & 31) * 256;            // M=8192
      col0 = 0;                           // N=128
      Ag = zproj ? kbr : qbf;
      Bg = zproj ? Wkb : (Wqb + 2048LL * 1024);
    }
    const int lda = 1024, ldb = 1024;
    const int wr = (wv & 3) * 64;
    const int wc = (wv >> 2) * 64;

    const int rr0 = tid >> 3;
    const int swz = ((tid & 7) ^ (rr0 & 7)) * 8;
    const unsigned short* gA0 = Ag + (long long)(row0 + rr0) * lda + swz;
    const unsigned short* gB0 = Bg + (long long)(col0 + rr0) * ldb + swz;
    const long long sA64 = 64LL * lda, sB64 = 64LL * ldb;
    unsigned short* lA0 = &Ls[0]     + tid * 8;
    unsigned short* lB0 = &Ls[16384] + tid * 8;

    floatx4 acc[4][4];
    #pragma unroll
    for (int i = 0; i < 4; i++)
      #pragma unroll
      for (int j = 0; j < 4; j++) acc[i][j] = zero;

    const int NT = 16; // K=1024

    #pragma unroll
    for (int i = 0; i < 4; i++) ASYNC_LD16(gA0 + i * sA64,      lA0 + i * 4096);
    #pragma unroll
    for (int i = 0; i < 2; i++) ASYNC_LD16(gB0 + i * sB64,      lB0 + i * 4096);
    #pragma unroll
    for (int i = 0; i < 4; i++) ASYNC_LD16(gA0 + i * sA64 + 64, lA0 + i * 4096 + 24576);
    #pragma unroll
    for (int i = 0; i < 2; i++) ASYNC_LD16(gB0 + i * sB64 + 64, lB0 + i * 4096 + 24576);
    asm volatile("s_waitcnt vmcnt(6)" ::: "memory");
    SBAR();

    for (int t = 0; t < NT; ++t) {
      const int cb = (t & 1) * 24576;
      const unsigned short* Ab = &Ls[cb];
      const unsigned short* Bb = &Ls[cb + 16384];
      const bool st = (t + 2) < NT;
      const int kt2 = (t + 2) << 6;

      short8 afA[4][2], bfv[4][2];

      // ---- phase 1: all 16 ds_reads; lgkm-gate; 16 MFMA (ni0-1)
      #pragma unroll
      for (int mi = 0; mi < 4; mi++)
        #pragma unroll
        for (int kk = 0; kk < 2; kk++)
          afA[mi][kk] = *(const short8*)(Ab + (wr + mi*16 + lr) * 64 + (((kk<<2) + lq) ^ r7) * 8);
      #pragma unroll
      for (int ni = 0; ni < 4; ni++)
        #pragma unroll
        for (int kk = 0; kk < 2; kk++)
          bfv[ni][kk] = *(const short8*)(Bb + (wc + ni*16 + lr) * 64 + (((kk<<2) + lq) ^ r7) * 8);
      LGKM0();
      __builtin_amdgcn_sched_barrier(0);
      __builtin_amdgcn_s_setprio(1);
      #pragma unroll
      for (int mi = 0; mi < 4; mi++)
        #pragma unroll
        for (int ni = 0; ni < 2; ni++)
          #pragma unroll
          for (int kk = 0; kk < 2; kk++)
            acc[mi][ni] = MFMA_BF16(afA[mi][kk], bfv[ni][kk], acc[mi][ni], 0, 0, 0);
      __builtin_amdgcn_s_setprio(0);
      SBAR();   // all waves' reads of tile t complete -> buffer slots free

      // ---- phase 2: stage t+2 (same-parity buffer); 16 MFMA (ni2-3, regs)
      if (st) {
        #pragma unroll
        for (int i = 0; i < 4; i++) ASYNC_LD16(gA0 + i * sA64 + kt2, lA0 + i * 4096 + cb);
        #pragma unroll
        for (int i = 0; i < 2; i++) ASYNC_LD16(gB0 + i * sB64 + kt2, lB0 + i * 4096 + cb);
      }
      __builtin_amdgcn_s_setprio(1);
      #pragma unroll
      for (int mi = 0; mi < 4; mi++)
        #pragma unroll
        for (int ni = 0; ni < 2; ni++)
          #pragma unroll
          for (int kk = 0; kk < 2; kk++)
            acc[mi][ni+2] = MFMA_BF16(afA[mi][kk], bfv[ni+2][kk], acc[mi][ni+2], 0, 0, 0);
      __builtin_amdgcn_s_setprio(0);
      if (st) { asm volatile("s_waitcnt vmcnt(6)" ::: "memory"); }
      else    { asm volatile("s_waitcnt vmcnt(0)" ::: "memory"); }
      SBAR();
    }

    // epilogues
    if (zproj < 0) {
      // g2: vT[b][e][s] = silu(v + bv[e]), coalesced along s
      #pragma unroll
      for (int mi = 0; mi < 4; mi++)
        #pragma unroll
        for (int ni = 0; ni < 4; ni++)
          #pragma unroll
          for (int r = 0; r < 4; r++) {
            const int gm = row0 + wr + mi * 16 + lq * 4 + r;
            const int gn = col0 + wc + ni * 16 + lr;
            const float v = acc[mi][ni][r] + bv[gm];
            const int b = gn >> 11, s = gn & 2047;
            vT[((long long)b * 1024 + gm) * 2048 + s] = f2u(siluf_(v));
          }
    } else {
      const float* bias = zproj ? bk : (bq + 2048);
      const float* gam  = zproj ? (gamma + 128) : gamma;
      const float* bet  = zproj ? (beta + 128)  : beta;
      unsigned short* ob = zproj ? kpj : qpj;
      #pragma unroll
      for (int mi = 0; mi < 4; mi++)
        #pragma unroll
        for (int ni = 0; ni < 4; ni++)
          #pragma unroll
          for (int r = 0; r < 4; r++) {
            const int gm = row0 + wr + mi * 16 + lq * 4 + r;
            const int gn = wc + ni * 16 + lr;
            const float v = acc[mi][ni][r] + bias[gn];
            ob[(long long)gm * 128 + gn] = f2u(siluf_(v) * gam[gn] + bet[gn]);
          }
    }
  }
}

// ---------------------------------------------------------------- 256x128 counted-vmcnt GEMM (g5, R4-exact)
__global__ __launch_bounds__(512, 2)
void gemm_g5(const unsigned short* __restrict__ A, int lda,
             const unsigned short* __restrict__ Bm, int ldb,
             int K,
             const float* __restrict__ bias,
             float* __restrict__ f0,
             const unsigned short* __restrict__ rmul,
             const float* __restrict__ qin)
{
  __shared__ __align__(16) unsigned short Ls[49152]; // 96 KiB

  const int tid = threadIdx.x;
  const int bm = blockIdx.x, bn = blockIdx.y;
  const int row0 = bm * 256;
  const int col0 = bn * 128;

  const int lane = tid & 63;
  const int wv   = tid >> 6;
  const int wr   = (wv & 3) * 64;
  const int wc   = (wv >> 2) * 64;
  const int lr   = lane & 15;
  const int lq   = lane >> 4;
  const int r7   = lr & 7;

  const int rr0 = tid >> 3;
  const int swz = ((tid & 7) ^ (rr0 & 7)) * 8;
  const unsigned short* gA0 = A  + (long long)(row0 + rr0) * lda + swz;
  const unsigned short* gB0 = Bm + (long long)(col0 + rr0) * ldb + swz;
  const long long sA64 = 64LL * lda, sB64 = 64LL * ldb;
  unsigned short* lA0 = &Ls[0]     + tid * 8;
  unsigned short* lB0 = &Ls[16384] + tid * 8;

  floatx4 acc[4][4];
  const floatx4 zero = {0.f, 0.f, 0.f, 0.f};
  #pragma unroll
  for (int i = 0; i < 4; i++)
    #pragma unroll
    for (int j = 0; j < 4; j++) acc[i][j] = zero;

  const int NT = K >> 6;

  #pragma unroll
  for (int i = 0; i < 4; i++) ASYNC_LD16(gA0 + i * sA64,      lA0 + i * 4096);
  #pragma unroll
  for (int i = 0; i < 2; i++) ASYNC_LD16(gB0 + i * sB64,      lB0 + i * 4096);
  #pragma unroll
  for (int i = 0; i < 4; i++) ASYNC_LD16(gA0 + i * sA64 + 64, lA0 + i * 4096 + 24576);
  #pragma unroll
  for (int i = 0; i < 2; i++) ASYNC_LD16(gB0 + i * sB64 + 64, lB0 + i * 4096 + 24576);
  asm volatile("s_waitcnt vmcnt(6)" ::: "memory");
  SBAR();

  for (int t = 0; t < NT; ++t) {
    const int cb = (t & 1) * 24576;
    const unsigned short* Ab = &Ls[cb];
    const unsigned short* Bb = &Ls[cb + 16384];
    const bool st = (t + 2) < NT;
    const int kt2 = (t + 2) << 6;

    short8 afA[4][2], bfv[4][2];

    #pragma unroll
    for (int mi = 0; mi < 4; mi++)
      #pragma unroll
      for (int kk = 0; kk < 2; kk++)
        afA[mi][kk] = *(const short8*)(Ab + (wr + mi*16 + lr) * 64 + (((kk<<2) + lq) ^ r7) * 8);
    #pragma unroll
    for (int ni = 0; ni < 4; ni++)
      #pragma unroll
      for (int kk = 0; kk < 2; kk++)
        bfv[ni][kk] = *(const short8*)(Bb + (wc + ni*16 + lr) * 64 + (((kk<<2) + lq) ^ r7) * 8);
    LGKM0();
    __builtin_amdgcn_sched_barrier(0);
    __builtin_amdgcn_s_setprio(1);
    #pragma unroll
    for (int mi = 0; mi < 4; mi++)
      #pragma unroll
      for (int ni = 0; ni < 2; ni++)
        #pragma unroll
        for (int kk = 0; kk < 2; kk++)
          acc[mi][ni] = MFMA_BF16(afA[mi][kk], bfv[ni][kk], acc[mi][ni], 0, 0, 0);
    __builtin_amdgcn_s_setprio(0);
    SBAR();

    if (st) {
      #pragma unroll
      for (int i = 0; i < 4; i++) ASYNC_LD16(gA0 + i * sA64 + kt2, lA0 + i * 4096 + cb);
      #pragma unroll
      for (int i = 0; i < 2; i++) ASYNC_LD16(gB0 + i * sB64 + kt2, lB0 + i * 4096 + cb);
    }
    __builtin_amdgcn_s_setprio(1);
    #pragma unroll
    for (int mi = 0; mi < 4; mi++)
      #pragma unroll
      for (int ni = 0; ni < 2; ni++)
        #pragma unroll
        for (int kk = 0; kk < 2; kk++)
          acc[mi][ni+2] = MFMA_BF16(afA[mi][kk], bfv[ni+2][kk], acc[mi][ni+2], 0, 0, 0);
    __builtin_amdgcn_s_setprio(0);
    if (st) { asm volatile("s_waitcnt vmcnt(6)" ::: "memory"); }
    else    { asm volatile("s_waitcnt vmcnt(0)" ::: "memory"); }
    SBAR();
  }

  #pragma unroll
  for (int mi = 0; mi < 4; mi++)
    #pragma unroll
    for (int ni = 0; ni < 4; ni++)
      #pragma unroll
      for (int r = 0; r < 4; r++) {
        const int gm = row0 + wr + mi * 16 + lq * 4 + r;
        const int gn = col0 + wc + ni * 16 + lr;
        const long long idx = (long long)gm * 1024 + gn;
        const float tv = tanhf(acc[mi][ni][r] + bias[gn]);
        const float qv = qin[idx];
        f0[idx] = qv + u2f(rmul[idx]) * (tv - qv);
      }
}

// ---------------------------------------------------------------- fused attention (R7-exact, 75us measured)
__global__ __launch_bounds__(512, 2)
void attn_fused(const unsigned short* __restrict__ qpj,  // (T,B,Z)
                const unsigned short* __restrict__ kpj,  // [B][S][Z]
                const unsigned short* __restrict__ vT,   // [B][E][S]
                const unsigned short* __restrict__ rbf,  // (T*B, E)
                unsigned short* __restrict__ hrb)        // (T*B, E) = h*r
{
  __shared__ __align__(16) unsigned short Vs[32768];     // 512 e-rows x 64 s
  __shared__ __align__(16) unsigned short Ks[2][8192];   // 64 s-rows x 128 Z dbuf
  __shared__ __align__(16) unsigned short Ps[4096];      // 64 t x 64 s
  __shared__ float rsl[64];

  const int tid = threadIdx.x;
  const int eh = blockIdx.x, ty = blockIdx.y, bz = blockIdx.z;
  const int t0 = ty * 64;

  const int lane = tid & 63;
  const int wv   = tid >> 6;
  const int lr   = lane & 15;
  const int lq   = lane >> 4;
  const int mi_s = wv & 3;
  const int niA  = (wv >> 2) * 2;

  const unsigned short* kb_g = kpj + (long long)bz * 2048 * 128;
  const unsigned short* vb_g = vT  + (long long)bz * 1024 * 2048;

  short8 afq[4];
  {
    const unsigned short* qrow = qpj + (long long)bz * 128
                               + (long long)(t0 + mi_s * 16 + lr) * 512;
    #pragma unroll
    for (int kd = 0; kd < 4; kd++)
      afq[kd] = *(const short8*)(qrow + (kd * 4 + lq) * 8);
  }

  const int rrV = tid >> 3;
  const int gcV = ((tid & 7) ^ (rrV & 7)) * 8;
  const unsigned short* gV0 = vb_g + (long long)(eh * 512 + rrV) * 2048 + gcV;
  unsigned short* lV0 = Vs + tid * 8;
  const int rrK = tid >> 4;
  const int gcK = ((tid & 15) ^ (rrK & 15)) * 8;
  const unsigned short* gK0 = kb_g + (long long)rrK * 128 + gcK;
  unsigned short* lK0 = &Ks[0][0] + tid * 8;

  floatx4 acc[4][4];
  floatx4 accSum[4];
  const floatx4 zero = {0.f, 0.f, 0.f, 0.f};
  #pragma unroll
  for (int i = 0; i < 4; i++) {
    accSum[i] = zero;
    #pragma unroll
    for (int j = 0; j < 4; j++) acc[i][j] = zero;
  }
  const short ob = (short)0x3F80;
  const short8 ones = {ob, ob, ob, ob, ob, ob, ob, ob};

  #pragma unroll
  for (int i = 0; i < 2; i++) ASYNC_LD16(gK0 + i * 4096, lK0 + i * 4096);

  for (int t = 0; t < 32; ++t) {
    const unsigned short* Kb = &Ks[t & 1][0];
    const bool st = (t + 1) < 32;

    #pragma unroll
    for (int i = 0; i < 8; i++)
      ASYNC_LD16(gV0 + (long long)i * 131072 + t * 64, lV0 + i * 4096);
    if (st) {
      unsigned short* lKn = &Ks[(t + 1) & 1][0] + tid * 8;
      #pragma unroll
      for (int i = 0; i < 2; i++)
        ASYNC_LD16(gK0 + (long long)(t + 1) * 8192 + i * 4096, lKn + i * 4096);
    }
    if (st) { asm volatile("s_waitcnt vmcnt(10)" ::: "memory"); }
    else    { asm volatile("s_waitcnt vmcnt(8)"  ::: "memory"); }
    SBAR();

    floatx4 accS[2] = {zero, zero};
    short8 bfk[2][4];
    #pragma unroll
    for (int f = 0; f < 2; f++)
      #pragma unroll
      for (int kd = 0; kd < 4; kd++)
        bfk[f][kd] = *(const short8*)(Kb + ((niA + f) * 16 + lr) * 128
                                         + (((kd * 4 + lq) ^ lr) & 15) * 8);
    #pragma unroll
    for (int f = 0; f < 2; f++)
      #pragma unroll
      for (int kd = 0; kd < 4; kd++)
        accS[f] = MFMA_BF16(afq[kd], bfk[f][kd], accS[f], 0, 0, 0);
    #pragma unroll
    for (int f = 0; f < 2; f++) {
      const int nif = niA + f;
      #pragma unroll
      for (int r = 0; r < 4; r++) {
        const float e = __expf(accS[f][r] * SCALING);
        const int trow = mi_s * 16 + lq * 4 + r;
        const int scol = nif * 16 + lr;
        const int slot = (scol >> 3) ^ (trow & 7);
        Ps[trow * 64 + slot * 8 + (lr & 7)] = f2u(e);
      }
    }
    LGKM0();
    if (st) { asm volatile("s_waitcnt vmcnt(2)" ::: "memory"); }
    else    { asm volatile("s_waitcnt vmcnt(0)" ::: "memory"); }
    SBAR();

    short8 afP[4][2], bfv[4][2];
    #pragma unroll
    for (int mi = 0; mi < 4; mi++)
      #pragma unroll
      for (int k8 = 0; k8 < 2; k8++)
        afP[mi][k8] = *(const short8*)(Ps + (mi * 16 + lr) * 64
                                          + ((k8 * 4 + lq) ^ (lr & 7)) * 8);
    #pragma unroll
    for (int ni = 0; ni < 4; ni++)
      #pragma unroll
      for (int k8 = 0; k8 < 2; k8++)
        bfv[ni][k8] = *(const short8*)(Vs + (wv * 64 + ni * 16 + lr) * 64
                                          + ((k8 * 4 + lq) ^ (lr & 7)) * 8);
    __builtin_amdgcn_s_setprio(1);
    #pragma unroll
    for (int mi = 0; mi < 4; mi++)
      #pragma unroll
      for (int ni = 0; ni < 4; ni++)
        #pragma unroll
        for (int k8 = 0; k8 < 2; k8++)
          acc[mi][ni] = MFMA_BF16(afP[mi][k8], bfv[ni][k8], acc[mi][ni], 0, 0, 0);
    __builtin_amdgcn_s_setprio(0);
    if (wv == 0) {
      #pragma unroll
      for (int mi = 0; mi < 4; mi++)
        #pragma unroll
        for (int k8 = 0; k8 < 2; k8++)
          accSum[mi] = MFMA_BF16(afP[mi][k8], ones, accSum[mi], 0, 0, 0);
    }
    LGKM0();
    SBAR();
  }

  if (wv == 0 && lr == 0) {
    #pragma unroll
    for (int mi = 0; mi < 4; mi++)
      #pragma unroll
      for (int r = 0; r < 4; r++)
        rsl[mi * 16 + lq * 4 + r] = accSum[mi][r];
  }
  LGKM0();
  SBAR();
  #pragma unroll
  for (int mi = 0; mi < 4; mi++) {
    float iv[4];
    #pragma unroll
    for (int r = 0; r < 4; r++) iv[r] = 1.0f / rsl[mi * 16 + lq * 4 + r];
    #pragma unroll
    for (int ni = 0; ni < 4; ni++) {
      #pragma unroll
      for (int r = 0; r < 4; r++) {
        const int gt = t0 + mi * 16 + lq * 4 + r;
        const int ge = eh * 512 + wv * 64 + ni * 16 + lr;
        const long long idx = ((long long)gt * 4 + bz) * 1024 + ge;
        hrb[idx] = f2u(acc[mi][ni][r] * iv[r] * u2f(rbf[idx]));
      }
    }
  }
}

// ---------------------------------------------------------------- launch
extern "C" void kernel_launch(void* const* d_in, const int* in_sizes, int n_in,
                              void* d_out, int out_size, void* d_ws, size_t ws_size,
                              hipStream_t stream)
{
  (void)in_sizes; (void)n_in; (void)out_size; (void)ws_size;
  const float* query = (const float*)d_in[0];
  const float* key   = (const float*)d_in[1];
  const float* Wq    = (const float*)d_in[2];
  const float* bq    = (const float*)d_in[3];
  const float* Wk    = (const float*)d_in[4];
  const float* bk    = (const float*)d_in[5];
  const float* Wv    = (const float*)d_in[6];
  const float* bv    = (const float*)d_in[7];
  const float* Wh    = (const float*)d_in[8];
  const float* bh    = (const float*)d_in[9];
  const float* gamma = (const float*)d_in[10];
  const float* beta  = (const float*)d_in[11];
  float* out = (float*)d_out;

  char* p = (char*)d_ws;
  auto take = [&](size_t bytes) -> char* {
    char* r = p; p += (bytes + 255) & ~(size_t)255; return r;
  };
  unsigned short* qbf = (unsigned short*)take(8192ULL * 1024 * 2); // query bf16 (T*B,E)
  unsigned short* kbr = (unsigned short*)take(8192ULL * 1024 * 2); // key bf16 [B][S][E]
  unsigned short* Wqb = (unsigned short*)take(2176ULL * 1024 * 2);
  unsigned short* Wkb = (unsigned short*)take(128ULL  * 1024 * 2);
  unsigned short* Wvb = (unsigned short*)take(1024ULL * 1024 * 2);
  unsigned short* Whb = (unsigned short*)take(1024ULL * 1024 * 2);
  unsigned short* ub  = (unsigned short*)take(8192ULL * 1024 * 2); // u gate bf16
  unsigned short* rbf = (unsigned short*)take(8192ULL * 1024 * 2); // r bf16
  unsigned short* qpj = (unsigned short*)take(8192ULL * 128 * 2);  // q (T,B,Z)
  unsigned short* kpj = (unsigned short*)take(8192ULL * 128 * 2);  // k [B][S][Z]
  unsigned short* vT  = (unsigned short*)take(4ULL * 1024 * 2048 * 2); // v^T [B][E][S]
  unsigned short* hrb = (unsigned short*)take(8192ULL * 1024 * 2); // h*r bf16

  dim3 gblk(512);
  // 1: all casts, one dispatch (512 thr, 2 rows/block)
  cast_all<<<10368, gblk, 0, stream>>>(query, key, Wq, Wk, Wv, Wh,
      qbf, kbr, Wqb, Wkb, Wvb, Whb);
  // 2: g0 + g2 + both N=128 projections, one dispatch (576 blocks)
  mega<<<576, gblk, 0, stream>>>(qbf, Wqb, kbr, Wvb, Wkb,
      bq, bk, bv, gamma, beta, (float*)ub, rbf, vT, qpj, kpj);
  // 3: fused attention: hr = softmax(q k^T * scale) @ V * r
  attn_fused<<<dim3(2, 32, 4), gblk, 0, stream>>>(qpj, kpj, vT, rbf, hrb);
  // 4: out = query + u * (tanh(hr @ Wh^T + bh) - query)
  gemm_g5<<<dim3(32, 8, 1), gblk, 0, stream>>>(hrb, 1024, Whb, 1024, 1024,
      bh, out, ub, query);
}